// Round 3
// baseline (7266.766 us; speedup 1.0000x reference)
//
#include <hip/hip_runtime.h>
#include <math.h>

typedef short s16x8 __attribute__((ext_vector_type(8)));
typedef float f32x4 __attribute__((ext_vector_type(4)));

namespace {
constexpr int T = 80, Fdim = 32, H = 512, OSTR = 34;
constexpr size_t SB = 512 * 512;

__device__ __forceinline__ unsigned short f2bf(float f) {
  union { float f; unsigned u; } x; x.f = f;
  unsigned u = x.u; u += 0x7fffu + ((u >> 16) & 1u);
  return (unsigned short)(u >> 16);
}
__device__ __forceinline__ float bf2f(unsigned short s) {
  union { unsigned u; float f; } x; x.u = ((unsigned)s) << 16; return x.f;
}

// ---------------- weight pre-pack ----------------
// dst block (8KB) index = jb*NKC + kc: [strip(4)][half(2)][lane(64)][8 bf16]
// lane l holds W[n][k], k = kc*32 + (l>>4)*8 + i
// layer: n = strip*512 + jb*16 + (l&15);  head: n = jb*64 + strip*16 + (l&15)
__global__ __launch_bounds__(256)
void pack_w_kernel(const float* __restrict__ w1, const float* __restrict__ w2,
                   int K1, int K2, int NKC, int head, unsigned short* __restrict__ dst) {
  int bid = blockIdx.x;
  int jb = bid / NKC, kc = bid % NKC;
  int tid = threadIdx.x;
  int strip = tid >> 6, l = tid & 63;
  int nl = l & 15, kg = l >> 4;
  int n = head ? (jb * 64 + strip * 16 + nl) : (strip * 512 + jb * 16 + nl);
  s16x8 h8, l8;
  #pragma unroll
  for (int i = 0; i < 8; ++i) {
    int k = kc * 32 + kg * 8 + i;
    float v = (k < K1) ? w1[(size_t)n * K1 + k] : w2[(size_t)n * K2 + (k - K1)];
    unsigned short h = f2bf(v);
    h8[i] = (short)h;
    l8[i] = (short)f2bf(v - bf2f(h));
  }
  size_t base = (size_t)bid * 4096;
  *(s16x8*)&dst[base + (size_t)(strip * 2 + 0) * 512 + l * 8] = h8;
  *(s16x8*)&dst[base + (size_t)(strip * 2 + 1) * 512 + l * 8] = l8;
}

__global__ __launch_bounds__(256)
void bsum_kernel(const float* bi0, const float* bh0, const float* bi1, const float* bh1,
                 float* bs0, float* bs1) {
  int i = blockIdx.x * 256 + threadIdx.x;
  if (i < 2048) bs0[i] = bi0[i] + bh0[i];
  else { int j = i - 2048; bs1[j] = bi1[j] + bh1[j]; }
}

// ---------------- persistent whole-model kernel ----------------
__global__ __launch_bounds__(256, 1)
void persist_kernel(const float* __restrict__ x,
                    const unsigned short* __restrict__ Wp0,
                    const unsigned short* __restrict__ Wp1,
                    const unsigned short* __restrict__ Wpf1,
                    const unsigned short* __restrict__ Wpf2,
                    const float* __restrict__ bs0,
                    const float* __restrict__ bs1,
                    const float* __restrict__ fc1_b,
                    const float* __restrict__ fc2_b,
                    const float* __restrict__ fc3_w,
                    const float* __restrict__ fc3_b,
                    float* h0b0, float* h0b1, float* h1b0, float* h1b1,
                    float* c0, float* c1, float* y1, float* y2,
                    float* out, int* cnt)
{
  __shared__ unsigned short Ash[2][4096];
  __shared__ unsigned short Bsh[2][4096];
  __shared__ float Gs[4][64][16];

  const int tid = threadIdx.x;
  const int bid = blockIdx.x;
  const int w = tid >> 6, l = tid & 63;
  const int xcd = bid & 7, loc = bid >> 3;
  const int jb = xcd * 4 + (loc & 3);   // 0..31 (h-col block of 16)
  const int m = loc >> 2;               // 0..7  (batch block of 64)
  const int row0 = m * 64;
  const int j0 = jb * 16;
  const int srow = tid >> 2, skg = tid & 3;
  const int slane = skg * 16 + (srow & 15), smf = srow >> 4;

  int ph = 0;
  auto gbar = [&]() {
    ++ph;
    __syncthreads();
    if (tid == 0) {
      __threadfence();
      int v = __hip_atomic_fetch_add(&cnt[xcd * 64], 1, __ATOMIC_RELEASE,
                                     __HIP_MEMORY_SCOPE_AGENT);
      if (v == 32 * ph - 1)
        __hip_atomic_fetch_add(&cnt[512], 1, __ATOMIC_ACQ_REL,
                               __HIP_MEMORY_SCOPE_AGENT);
      while (__hip_atomic_load(&cnt[512], __ATOMIC_ACQUIRE,
                               __HIP_MEMORY_SCOPE_AGENT) < 8 * ph)
        __builtin_amdgcn_s_sleep(1);
      __threadfence();
    }
    __syncthreads();
  };

  // -------- fused LSTM layer tile: 64 rows x 16 h-cols x 4 gates --------
  auto lstm_gemm = [&](const float* a1, int a1s, int NC1, int NC,
                       const float* a2, const unsigned short* WpJ,
                       const float* bsum, float* cst, float* hout,
                       const float* fb) {
    f32x4 acc[4];
    #pragma unroll
    for (int mf = 0; mf < 4; ++mf) acc[mf] = {0.f, 0.f, 0.f, 0.f};
    auto stage = [&](int kc, int buf) {
      const unsigned short* gp = WpJ + (size_t)kc * 4096;
      s16x8 b0 = *(const s16x8*)&gp[(w * 2 + 0) * 512 + l * 8];
      s16x8 b1 = *(const s16x8*)&gp[(w * 2 + 1) * 512 + l * 8];
      *(s16x8*)&Bsh[buf][(w * 2 + 0) * 512 + l * 8] = b0;
      *(s16x8*)&Bsh[buf][(w * 2 + 1) * 512 + l * 8] = b1;
      const float* src; int ss, kb;
      if (kc < NC1) { src = a1; ss = a1s; kb = kc * 32; }
      else          { src = a2; ss = H;   kb = (kc - NC1) * 32; }
      const float* p = src + (size_t)(row0 + srow) * ss + kb + skg * 8;
      float v[8];
      *(float4*)&v[0] = *(const float4*)p;
      *(float4*)&v[4] = *(const float4*)(p + 4);
      if (fb != nullptr && kc == 0) {
        #pragma unroll
        for (int i = 0; i < 8; ++i) {
          int kcol = skg * 8 + i;
          if (kcol == 4 || kcol == 5) v[i] = fb[(row0 + srow) * OSTR + (kcol - 4)];
        }
      }
      s16x8 h8, l8;
      #pragma unroll
      for (int i = 0; i < 8; ++i) {
        unsigned short hh = f2bf(v[i]);
        h8[i] = (short)hh;
        l8[i] = (short)f2bf(v[i] - bf2f(hh));
      }
      *(s16x8*)&Ash[buf][(smf * 2 + 0) * 512 + slane * 8] = h8;
      *(s16x8*)&Ash[buf][(smf * 2 + 1) * 512 + slane * 8] = l8;
    };
    stage(0, 0);
    __syncthreads();
    for (int kc = 0; kc < NC; ++kc) {
      int buf = kc & 1;
      if (kc + 1 < NC) stage(kc + 1, buf ^ 1);
      s16x8 Bhi = *(const s16x8*)&Bsh[buf][(w * 2 + 0) * 512 + l * 8];
      s16x8 Blo = *(const s16x8*)&Bsh[buf][(w * 2 + 1) * 512 + l * 8];
      #pragma unroll
      for (int mf = 0; mf < 4; ++mf) {
        s16x8 Ahi = *(const s16x8*)&Ash[buf][(mf * 2 + 0) * 512 + l * 8];
        s16x8 Alo = *(const s16x8*)&Ash[buf][(mf * 2 + 1) * 512 + l * 8];
        acc[mf] = __builtin_amdgcn_mfma_f32_16x16x32_bf16(Ahi, Bhi, acc[mf], 0, 0, 0);
        acc[mf] = __builtin_amdgcn_mfma_f32_16x16x32_bf16(Ahi, Blo, acc[mf], 0, 0, 0);
        acc[mf] = __builtin_amdgcn_mfma_f32_16x16x32_bf16(Alo, Bhi, acc[mf], 0, 0, 0);
      }
      __syncthreads();
    }
    float bsv = bsum[w * 512 + j0 + (l & 15)];
    #pragma unroll
    for (int mf = 0; mf < 4; ++mf)
      #pragma unroll
      for (int r = 0; r < 4; ++r)
        Gs[w][mf * 16 + (l >> 4) * 4 + r][l & 15] = acc[mf][r] + bsv;
    __syncthreads();
    #pragma unroll
    for (int p2 = 0; p2 < 4; ++p2) {
      int idx = tid + p2 * 256;
      int rr = idx >> 4, cc = idx & 15;
      float gi = Gs[0][rr][cc], gf = Gs[1][rr][cc];
      float gg = Gs[2][rr][cc], go = Gs[3][rr][cc];
      size_t gx = (size_t)(row0 + rr) * H + j0 + cc;
      float si = 1.f / (1.f + expf(-gi));
      float sf = 1.f / (1.f + expf(-gf));
      float so = 1.f / (1.f + expf(-go));
      float c2v = sf * cst[gx] + si * tanhf(gg);
      cst[gx] = c2v;
      hout[gx] = so * tanhf(c2v);
    }
    __syncthreads();
  };

  // -------- head GEMM: Y = gelu(A @ W^T + b), 64 WGs of 64x64 tiles --------
  auto head_gemm = [&](const float* A, const unsigned short* Wp,
                       const float* bias, float* Y) {
    if (bid < 64) {
      const int cb = bid & 7, mh = bid >> 3;
      const int hrow0 = mh * 64, hj0 = cb * 64;
      const int wm = w >> 1, wn = w & 1;
      f32x4 acc[2][2];
      #pragma unroll
      for (int a = 0; a < 2; ++a)
        #pragma unroll
        for (int b2 = 0; b2 < 2; ++b2) acc[a][b2] = {0.f, 0.f, 0.f, 0.f};
      auto hstage = [&](int kc, int buf) {
        const unsigned short* gp = Wp + (size_t)(cb * 16 + kc) * 4096;
        s16x8 b0 = *(const s16x8*)&gp[(w * 2 + 0) * 512 + l * 8];
        s16x8 b1 = *(const s16x8*)&gp[(w * 2 + 1) * 512 + l * 8];
        *(s16x8*)&Bsh[buf][(w * 2 + 0) * 512 + l * 8] = b0;
        *(s16x8*)&Bsh[buf][(w * 2 + 1) * 512 + l * 8] = b1;
        const float* p = A + (size_t)(hrow0 + srow) * H + kc * 32 + skg * 8;
        float v[8];
        *(float4*)&v[0] = *(const float4*)p;
        *(float4*)&v[4] = *(const float4*)(p + 4);
        s16x8 h8, l8;
        #pragma unroll
        for (int i = 0; i < 8; ++i) {
          unsigned short hh = f2bf(v[i]);
          h8[i] = (short)hh;
          l8[i] = (short)f2bf(v[i] - bf2f(hh));
        }
        *(s16x8*)&Ash[buf][(smf * 2 + 0) * 512 + slane * 8] = h8;
        *(s16x8*)&Ash[buf][(smf * 2 + 1) * 512 + slane * 8] = l8;
      };
      hstage(0, 0);
      __syncthreads();
      for (int kc = 0; kc < 16; ++kc) {
        int buf = kc & 1;
        if (kc + 1 < 16) hstage(kc + 1, buf ^ 1);
        #pragma unroll
        for (int nf = 0; nf < 2; ++nf) {
          s16x8 Bhi = *(const s16x8*)&Bsh[buf][((wn * 2 + nf) * 2 + 0) * 512 + l * 8];
          s16x8 Blo = *(const s16x8*)&Bsh[buf][((wn * 2 + nf) * 2 + 1) * 512 + l * 8];
          #pragma unroll
          for (int mf = 0; mf < 2; ++mf) {
            s16x8 Ahi = *(const s16x8*)&Ash[buf][((wm * 2 + mf) * 2 + 0) * 512 + l * 8];
            s16x8 Alo = *(const s16x8*)&Ash[buf][((wm * 2 + mf) * 2 + 1) * 512 + l * 8];
            acc[mf][nf] = __builtin_amdgcn_mfma_f32_16x16x32_bf16(Ahi, Bhi, acc[mf][nf], 0, 0, 0);
            acc[mf][nf] = __builtin_amdgcn_mfma_f32_16x16x32_bf16(Ahi, Blo, acc[mf][nf], 0, 0, 0);
            acc[mf][nf] = __builtin_amdgcn_mfma_f32_16x16x32_bf16(Alo, Bhi, acc[mf][nf], 0, 0, 0);
          }
        }
        __syncthreads();
      }
      #pragma unroll
      for (int mf = 0; mf < 2; ++mf)
        #pragma unroll
        for (int nf = 0; nf < 2; ++nf) {
          int col = hj0 + (wn * 2 + nf) * 16 + (l & 15);
          float bv = bias[col];
          #pragma unroll
          for (int r = 0; r < 4; ++r) {
            int row = hrow0 + (wm * 2 + mf) * 16 + (l >> 4) * 4 + r;
            float vv = acc[mf][nf][r] + bv;
            Y[(size_t)row * H + col] = 0.5f * vv * (1.f + erff(vv * 0.70710678118654752f));
          }
        }
      __syncthreads();
    }
  };

  auto fc3 = [&](int kidx) {
    int b = bid * 2 + (w >> 1), o = w & 1;
    const float* yr = y2 + (size_t)b * H + l * 8;
    const float* wr = fc3_w + (size_t)o * H + l * 8;
    float s = 0.f;
    #pragma unroll
    for (int i = 0; i < 8; ++i) s += yr[i] * wr[i];
    #pragma unroll
    for (int d = 32; d > 0; d >>= 1) s += __shfl_down(s, d, 64);
    if (l == 0) out[b * OSTR + kidx * 2 + o] = s + fc3_b[o];
  };

  const unsigned short* Wp0J = Wp0 + (size_t)jb * 17 * 4096;
  const unsigned short* Wp1J = Wp1 + (size_t)jb * 32 * 4096;
  auto h0at = [&](int t) { return (t & 1) ? h0b1 : h0b0; };
  auto h1at = [&](int t) { return (t & 1) ? h1b1 : h1b0; };

  // warmup, software-pipelined: phase t does {L1_{t-1}, L0_t}, 1 barrier/step
  for (int t = 0; t < 64; ++t) {
    if (t > 0)
      lstm_gemm(h0at(t - 1), H, 16, 32, h1at(t), Wp1J, bs1, c1, h1at(t - 1), nullptr);
    lstm_gemm(x + (size_t)t * Fdim, T * Fdim, 1, 17, h0at(t + 1), Wp0J, bs0,
              c0, h0at(t), nullptr);
    gbar();
  }
  lstm_gemm(h0at(63), H, 16, 32, h1at(62), Wp1J, bs1, c1, h1at(63), nullptr);
  gbar();

  // AR tail: head(h1_t) -> out_kidx -> feeds L0_{t+1}
  for (int kidx = 0; kidx < 17; ++kidx) {
    int t = 63 + kidx;
    head_gemm(h1at(t), Wpf1, fc1_b, y1); gbar();
    head_gemm(y1, Wpf2, fc2_b, y2); gbar();
    fc3(kidx); gbar();
    if (kidx < 16) {
      int s = 64 + kidx;
      lstm_gemm(x + (size_t)s * Fdim, T * Fdim, 1, 17, h0at(s + 1), Wp0J, bs0,
                c0, h0at(s), out + kidx * 2);
      gbar();
      lstm_gemm(h0at(s), H, 16, 32, h1at(s + 1), Wp1J, bs1, c1, h1at(s), nullptr);
      gbar();
    }
  }
}

} // namespace

extern "C" void kernel_launch(void* const* d_in, const int* in_sizes, int n_in,
                              void* d_out, int out_size, void* d_ws, size_t ws_size,
                              hipStream_t stream) {
  const float* x     = (const float*)d_in[0];
  const float* w_ih0 = (const float*)d_in[1];
  const float* w_hh0 = (const float*)d_in[2];
  const float* b_ih0 = (const float*)d_in[3];
  const float* b_hh0 = (const float*)d_in[4];
  const float* w_ih1 = (const float*)d_in[5];
  const float* w_hh1 = (const float*)d_in[6];
  const float* b_ih1 = (const float*)d_in[7];
  const float* b_hh1 = (const float*)d_in[8];
  const float* fc1_w = (const float*)d_in[9];
  const float* fc1_b = (const float*)d_in[10];
  const float* fc2_w = (const float*)d_in[11];
  const float* fc2_b = (const float*)d_in[12];
  const float* fc3_w = (const float*)d_in[13];
  const float* fc3_b = (const float*)d_in[14];
  float* out = (float*)d_out;
  char* wsb = (char*)d_ws;

  constexpr size_t O_WP0  = 0;                       // 32*17*8192 = 4456448
  constexpr size_t O_WP1  = 4456448;                 // 32*32*8192 = 8388608
  constexpr size_t O_WPF1 = O_WP1 + 8388608;         // 8*16*8192 = 1048576
  constexpr size_t O_WPF2 = O_WPF1 + 1048576;
  constexpr size_t O_BS0  = O_WPF2 + 1048576;        // 8192
  constexpr size_t O_BS1  = O_BS0 + 8192;
  constexpr size_t O_CNT  = O_BS1 + 8192;            // 4096
  constexpr size_t O_ACT  = O_CNT + 4096;

  unsigned short* Wp0  = (unsigned short*)(wsb + O_WP0);
  unsigned short* Wp1  = (unsigned short*)(wsb + O_WP1);
  unsigned short* Wpf1 = (unsigned short*)(wsb + O_WPF1);
  unsigned short* Wpf2 = (unsigned short*)(wsb + O_WPF2);
  float* bs0 = (float*)(wsb + O_BS0);
  float* bs1 = (float*)(wsb + O_BS1);
  int* cnt   = (int*)(wsb + O_CNT);
  float* acts = (float*)(wsb + O_ACT);

  float* h0b1 = acts;            // zeroed
  float* h1b1 = acts + SB;       // zeroed
  float* c0   = acts + 2 * SB;   // zeroed
  float* c1   = acts + 3 * SB;   // zeroed
  float* h0b0 = acts + 4 * SB;
  float* h1b0 = acts + 5 * SB;
  float* y1   = acts + 6 * SB;
  float* y2   = acts + 7 * SB;

  pack_w_kernel<<<dim3(32 * 17), 256, 0, stream>>>(w_ih0, w_hh0, 32, 512, 17, 0, Wp0);
  pack_w_kernel<<<dim3(32 * 32), 256, 0, stream>>>(w_ih1, w_hh1, 512, 512, 32, 0, Wp1);
  pack_w_kernel<<<dim3(8 * 16), 256, 0, stream>>>(fc1_w, fc1_w, 512, 512, 16, 1, Wpf1);
  pack_w_kernel<<<dim3(8 * 16), 256, 0, stream>>>(fc2_w, fc2_w, 512, 512, 16, 1, Wpf2);
  bsum_kernel<<<dim3(16), 256, 0, stream>>>(b_ih0, b_hh0, b_ih1, b_hh1, bs0, bs1);
  hipMemsetAsync(cnt, 0, 4096, stream);
  hipMemsetAsync(acts, 0, 4 * SB * sizeof(float), stream);

  persist_kernel<<<dim3(256), dim3(256), 0, stream>>>(
      x, Wp0, Wp1, Wpf1, Wpf2, bs0, bs1, fc1_b, fc2_b, fc3_w, fc3_b,
      h0b0, h0b1, h1b0, h1b1, c0, c1, y1, y2, out, cnt);
}

// Round 7
// 5218.892 us; speedup vs baseline: 1.3924x; 1.3924x over previous
//
#include <hip/hip_runtime.h>
#include <math.h>

typedef short s16x4 __attribute__((ext_vector_type(4)));
typedef short s16x8 __attribute__((ext_vector_type(8)));
typedef float f32x4 __attribute__((ext_vector_type(4)));
typedef unsigned short us;
typedef unsigned long long ull;

namespace {
constexpr int T = 80, Fdim = 32, H = 512, OSTR = 34;

__device__ __forceinline__ us f2bf(float f) {
  union { float f; unsigned u; } x; x.f = f;
  unsigned u = x.u; u += 0x7fffu + ((u >> 16) & 1u);
  return (us)(u >> 16);
}
__device__ __forceinline__ float bf2f(us s) {
  union { unsigned u; float f; } x; x.u = ((unsigned)s) << 16; return x.f;
}
__device__ __forceinline__ float sigf(float v) { return 1.f / (1.f + expf(-v)); }
__device__ __forceinline__ float geluf(float v) {
  return 0.5f * v * (1.f + erff(v * 0.70710678118654752f));
}

// device-coherent (cross-XCD) 8B data movement, fully compiler-managed
__device__ __forceinline__ ull ald8(const void* p) {
  return __hip_atomic_load((const ull*)p, __ATOMIC_RELAXED, __HIP_MEMORY_SCOPE_AGENT);
}
__device__ __forceinline__ void ast8(void* p, ull v) {
  __hip_atomic_store((ull*)p, v, __ATOMIC_RELAXED, __HIP_MEMORY_SCOPE_AGENT);
}

union U8 { ull u; s16x4 v4; float f[2]; };
union S8 { s16x8 v; ull u[2]; };

// ---------------- weight pre-pack ----------------
// block (8KB) idx = jb*NKC + kc: [strip(4)][half(2)][lane(64)][8 bf16]
__global__ __launch_bounds__(256)
void pack_w_kernel(const float* __restrict__ w1, const float* __restrict__ w2,
                   int K1, int K2, int NKC, int head, us* __restrict__ dst) {
  int bid = blockIdx.x;
  int jb = bid / NKC, kc = bid % NKC;
  int tid = threadIdx.x;
  int strip = tid >> 6, l = tid & 63;
  int nl = l & 15, kg = l >> 4;
  int n = head ? (jb * 64 + strip * 16 + nl) : (strip * 512 + jb * 16 + nl);
  s16x8 h8, l8;
  #pragma unroll
  for (int i = 0; i < 8; ++i) {
    int k = kc * 32 + kg * 8 + i;
    float v = (k < K1) ? w1[(size_t)n * K1 + k] : w2[(size_t)n * K2 + (k - K1)];
    us h = f2bf(v);
    h8[i] = (short)h;
    l8[i] = (short)f2bf(v - bf2f(h));
  }
  size_t base = (size_t)bid * 4096;
  *(s16x8*)&dst[base + (size_t)(strip * 2 + 0) * 512 + l * 8] = h8;
  *(s16x8*)&dst[base + (size_t)(strip * 2 + 1) * 512 + l * 8] = l8;
}

__global__ __launch_bounds__(256)
void bsum_kernel(const float* bi0, const float* bh0, const float* bi1, const float* bh1,
                 float* bs0, float* bs1) {
  int i = blockIdx.x * 256 + threadIdx.x;
  if (i < 2048) bs0[i] = bi0[i] + bh0[i];
  else { int j = i - 2048; bs1[j] = bi1[j] + bh1[j]; }
}

// ---------------- persistent whole-model kernel ----------------
__global__ __launch_bounds__(256, 1)
void persist_kernel(const float* __restrict__ x,
                    const us* __restrict__ Wp0, const us* __restrict__ Wp1,
                    const us* __restrict__ Wpf1, const us* __restrict__ Wpf2,
                    const float* __restrict__ bs0, const float* __restrict__ bs1,
                    const float* __restrict__ fc1_b, const float* __restrict__ fc2_b,
                    const float* __restrict__ fc3_w, const float* __restrict__ fc3_b,
                    us* hp0_0, us* hp0_1, us* hp1_0, us* hp1_1,
                    float* c0, float* c1, us* y1p, float* y2,
                    float* out, int* cnt)
{
  __shared__ __align__(16) us Ash[2][4096];
  __shared__ __align__(16) us Bsh[2][2][4096];
  __shared__ __align__(16) float Gs[4][64][16];

  const int tid = threadIdx.x;
  const int bid = blockIdx.x;
  const int w = tid >> 6, l = tid & 63;
  const int xcd = bid & 7, loc = bid >> 3;
  const int jb = xcd * 4 + (loc & 3);   // 0..31 (h-col block of 16)
  const int m = loc >> 2;               // 0..7  (batch block of 64)
  const int row0 = m * 64;
  const int j0 = jb * 16;
  const int base31 = j0 & 31;

  const us* WpJ0 = Wp0 + (size_t)jb * 17 * 4096;
  const us* WpJ1 = Wp1 + (size_t)jb * 32 * 4096;

  int ph = 0;
  auto gbar = [&]() {
    ++ph;
    __syncthreads();   // all threads' stores drained (vmcnt 0 per wave)
    if (tid == 0) {
      int v = __hip_atomic_fetch_add(&cnt[xcd * 64], 1, __ATOMIC_RELEASE,
                                     __HIP_MEMORY_SCOPE_AGENT);
      if (v == 32 * ph - 1)
        __hip_atomic_fetch_add(&cnt[512], 1, __ATOMIC_RELEASE,
                               __HIP_MEMORY_SCOPE_AGENT);
      while (__hip_atomic_load(&cnt[512], __ATOMIC_RELAXED,
                               __HIP_MEMORY_SCOPE_AGENT) < 8 * ph)
        __builtin_amdgcn_s_sleep(2);
      __builtin_amdgcn_fence(__ATOMIC_ACQUIRE, "workgroup");  // order only; no L2 inv
    }
    __syncthreads();
  };

  // ---------- fused LSTM phase: {L1(t-1) if DO1} + {L0(t) if DO0} ----------
  auto fused = [&](bool DO1, bool DO0, int t, bool use_fb, int kidx) {
    const us* h0prev = ((t + 1) & 1) ? hp0_1 : hp0_0;
    const us* h1prev = (t & 1) ? hp1_1 : hp1_0;
    us* h1w = ((t + 1) & 1) ? hp1_1 : hp1_0;
    us* h0w = (t & 1) ? hp0_1 : hp0_0;

    f32x4 acc0[4], acc1[4];
    #pragma unroll
    for (int mf = 0; mf < 4; ++mf) {
      acc0[mf] = {0.f, 0.f, 0.f, 0.f};
      acc1[mf] = {0.f, 0.f, 0.f, 0.f};
    }
    const int NP = DO1 ? 32 : 16;

    ull ra0, ra1, ra2, ra3;
    s16x8 rb10, rb11, rb00, rb01;
    auto stage_regs = [&](int kc) {
      const us* a = ((kc < 16) ? h0prev : h1prev) + (size_t)(m * 16 + (kc & 15)) * 4096;
      ra0 = ald8(a + tid * 8);
      ra1 = ald8(a + tid * 8 + 4);
      ra2 = ald8(a + 2048 + tid * 8);
      ra3 = ald8(a + 2048 + tid * 8 + 4);
      if (kc < 16) {
        if (DO1) { const us* b = WpJ1 + (size_t)kc * 4096;
                   rb10 = *(const s16x8*)(b + tid * 8);
                   rb11 = *(const s16x8*)(b + 2048 + tid * 8); }
        if (DO0) { const us* b = WpJ0 + (size_t)(kc + 1) * 4096;
                   rb00 = *(const s16x8*)(b + tid * 8);
                   rb01 = *(const s16x8*)(b + 2048 + tid * 8); }
      } else {
        const us* b = WpJ1 + (size_t)kc * 4096;
        rb10 = *(const s16x8*)(b + tid * 8);
        rb11 = *(const s16x8*)(b + 2048 + tid * 8);
      }
    };
    auto write_lds = [&](int buf, int kc) {
      *(ull*)&Ash[buf][tid * 8] = ra0;
      *(ull*)&Ash[buf][tid * 8 + 4] = ra1;
      *(ull*)&Ash[buf][2048 + tid * 8] = ra2;
      *(ull*)&Ash[buf][2048 + tid * 8 + 4] = ra3;
      if (kc < 16) {
        if (DO1) { *(s16x8*)&Bsh[buf][0][tid * 8] = rb10;
                   *(s16x8*)&Bsh[buf][0][2048 + tid * 8] = rb11; }
        if (DO0) { *(s16x8*)&Bsh[buf][1][tid * 8] = rb00;
                   *(s16x8*)&Bsh[buf][1][2048 + tid * 8] = rb01; }
      } else {
        *(s16x8*)&Bsh[buf][0][tid * 8] = rb10;
        *(s16x8*)&Bsh[buf][0][2048 + tid * 8] = rb11;
      }
    };
    auto lcomp = [&](int buf, bool c1on, bool c0on) {
      s16x8 B1h, B1l, B0h, B0l;
      if (c1on) { B1h = *(const s16x8*)&Bsh[buf][0][(w * 2 + 0) * 512 + l * 8];
                  B1l = *(const s16x8*)&Bsh[buf][0][(w * 2 + 1) * 512 + l * 8]; }
      if (c0on) { B0h = *(const s16x8*)&Bsh[buf][1][(w * 2 + 0) * 512 + l * 8];
                  B0l = *(const s16x8*)&Bsh[buf][1][(w * 2 + 1) * 512 + l * 8]; }
      #pragma unroll
      for (int mf = 0; mf < 4; ++mf) {
        s16x8 Ah = *(const s16x8*)&Ash[buf][(mf * 2 + 0) * 512 + l * 8];
        s16x8 Al = *(const s16x8*)&Ash[buf][(mf * 2 + 1) * 512 + l * 8];
        if (c1on) {
          acc1[mf] = __builtin_amdgcn_mfma_f32_16x16x32_bf16(Ah, B1h, acc1[mf], 0, 0, 0);
          acc1[mf] = __builtin_amdgcn_mfma_f32_16x16x32_bf16(Ah, B1l, acc1[mf], 0, 0, 0);
          acc1[mf] = __builtin_amdgcn_mfma_f32_16x16x32_bf16(Al, B1h, acc1[mf], 0, 0, 0);
        }
        if (c0on) {
          acc0[mf] = __builtin_amdgcn_mfma_f32_16x16x32_bf16(Ah, B0h, acc0[mf], 0, 0, 0);
          acc0[mf] = __builtin_amdgcn_mfma_f32_16x16x32_bf16(Ah, B0l, acc0[mf], 0, 0, 0);
          acc0[mf] = __builtin_amdgcn_mfma_f32_16x16x32_bf16(Al, B0h, acc0[mf], 0, 0, 0);
        }
      }
    };

    stage_regs(0);
    write_lds(0, 0);
    __syncthreads();
    for (int kc = 0; kc < NP; ++kc) {
      int buf = kc & 1;
      if (kc + 1 < NP) stage_regs(kc + 1);
      lcomp(buf, DO1, DO0 && (kc < 16));
      if (kc + 1 < NP) {
        __syncthreads();            // all waves done reading buf^1 (from kc-1)
        write_lds(buf ^ 1, kc + 1);
        __syncthreads();            // publish for next iteration
      }
    }

    if (DO0) {  // x chunk (L0 weight chunk 0) — plain staging
      __syncthreads();              // all waves done with last lcomp
      *(s16x8*)&Bsh[0][1][tid * 8] = *(const s16x8*)(WpJ0 + tid * 8);
      *(s16x8*)&Bsh[0][1][2048 + tid * 8] = *(const s16x8*)(WpJ0 + 2048 + tid * 8);
      int srow = tid >> 2, skg = tid & 3;
      const float* xp = x + (size_t)(row0 + srow) * (T * Fdim) + (size_t)t * Fdim + skg * 8;
      float v[8];
      #pragma unroll
      for (int i = 0; i < 8; ++i) v[i] = xp[i];
      if (use_fb && skg == 0) {
        const float* op = out + (size_t)(row0 + srow) * OSTR + kidx * 2;
        v[4] = __hip_atomic_load(op, __ATOMIC_RELAXED, __HIP_MEMORY_SCOPE_AGENT);
        v[5] = __hip_atomic_load(op + 1, __ATOMIC_RELAXED, __HIP_MEMORY_SCOPE_AGENT);
      }
      s16x8 h8, l8;
      #pragma unroll
      for (int i = 0; i < 8; ++i) {
        us hh = f2bf(v[i]);
        h8[i] = (short)hh;
        l8[i] = (short)f2bf(v[i] - bf2f(hh));
      }
      int slane = skg * 16 + (srow & 15), smf = srow >> 4;
      *(s16x8*)&Ash[0][(smf * 2 + 0) * 512 + slane * 8] = h8;
      *(s16x8*)&Ash[0][(smf * 2 + 1) * 512 + slane * 8] = l8;
      __syncthreads();
      lcomp(0, false, true);
    }

    // epilogue: stash gates -> cell -> packed coherent h write
    auto epi = [&](f32x4* acc, const float* bsum, float* cst, us* hw) {
      __syncthreads();
      float bsv = bsum[w * 512 + j0 + (l & 15)];
      #pragma unroll
      for (int mf = 0; mf < 4; ++mf)
        #pragma unroll
        for (int r = 0; r < 4; ++r)
          Gs[w][mf * 16 + (l >> 4) * 4 + r][l & 15] = acc[mf][r] + bsv;
      __syncthreads();
      int r = tid >> 2, sub = tid & 3, cc0 = sub * 4;
      float gvi[4], gvf[4], gvg[4], gvo[4], cv[4], cn[4], hv[4];
      #pragma unroll
      for (int q = 0; q < 4; ++q) {
        gvi[q] = Gs[0][r][cc0 + q]; gvf[q] = Gs[1][r][cc0 + q];
        gvg[q] = Gs[2][r][cc0 + q]; gvo[q] = Gs[3][r][cc0 + q];
      }
      size_t cix = (size_t)(row0 + r) * H + j0 + cc0;
      float4 cold = *(const float4*)&cst[cix];
      cv[0] = cold.x; cv[1] = cold.y; cv[2] = cold.z; cv[3] = cold.w;
      #pragma unroll
      for (int q = 0; q < 4; ++q) {
        float c2 = sigf(gvf[q]) * cv[q] + sigf(gvi[q]) * tanhf(gvg[q]);
        cn[q] = c2;
        hv[q] = sigf(gvo[q]) * tanhf(c2);
      }
      *(float4*)&cst[cix] = make_float4(cn[0], cn[1], cn[2], cn[3]);
      int kk = base31 + cc0;
      int kg = kk >> 3, i0 = kk & 7;
      int mf = r >> 4;
      int lane2 = kg * 16 + (r & 15);
      us* bb = hw + (size_t)(m * 16 + (j0 >> 5)) * 4096;
      U8 hh, hl;
      #pragma unroll
      for (int q = 0; q < 4; ++q) {
        us h2 = f2bf(hv[q]);
        hh.v4[q] = (short)h2;
        hl.v4[q] = (short)f2bf(hv[q] - bf2f(h2));
      }
      ast8(bb + (size_t)(mf * 2 + 0) * 512 + lane2 * 8 + i0, hh.u);
      ast8(bb + (size_t)(mf * 2 + 1) * 512 + lane2 * 8 + i0, hl.u);
      __syncthreads();
    };
    if (DO1) epi(acc1, bs1, c1, h1w);
    if (DO0) epi(acc0, bs0, c0, h0w);
  };

  // ---------- head GEMM: Y = gelu(A @ W^T + b); A packed bf16 hi/lo ----------
  // 128 WGs (mh 0..15 x cb 0..7), 32 rows x 64 cols each.
  auto headg = [&](const us* apack, const us* Wp, const float* bias,
                   float* yf, us* yp) {
    if (bid < 128) {
      const int mh = bid >> 3, cb = bid & 7;
      const int hrow0 = mh * 32, hj0 = cb * 64;
      f32x4 hacc[2];
      hacc[0] = {0.f, 0.f, 0.f, 0.f};
      hacc[1] = {0.f, 0.f, 0.f, 0.f};
      ull ra0, ra1; s16x8 rb0, rb1;
      auto hstage = [&](int kc) {
        const us* a = apack + (size_t)((mh >> 1) * 16 + kc) * 4096 + (mh & 1) * 2048;
        ra0 = ald8(a + tid * 8);
        ra1 = ald8(a + tid * 8 + 4);
        const us* b = Wp + (size_t)(cb * 16 + kc) * 4096;
        rb0 = *(const s16x8*)(b + tid * 8);
        rb1 = *(const s16x8*)(b + 2048 + tid * 8);
      };
      auto hwrite = [&](int buf) {
        *(ull*)&Ash[buf][tid * 8] = ra0;
        *(ull*)&Ash[buf][tid * 8 + 4] = ra1;
        *(s16x8*)&Bsh[buf][0][tid * 8] = rb0;
        *(s16x8*)&Bsh[buf][0][2048 + tid * 8] = rb1;
      };
      auto hcomp = [&](int buf) {
        int wm = w >> 1, wn = w & 1;
        s16x8 Ah = *(const s16x8*)&Ash[buf][(wm * 2 + 0) * 512 + l * 8];
        s16x8 Al = *(const s16x8*)&Ash[buf][(wm * 2 + 1) * 512 + l * 8];
        #pragma unroll
        for (int nf = 0; nf < 2; ++nf) {
          s16x8 Bh = *(const s16x8*)&Bsh[buf][0][((wn * 2 + nf) * 2 + 0) * 512 + l * 8];
          s16x8 Bl = *(const s16x8*)&Bsh[buf][0][((wn * 2 + nf) * 2 + 1) * 512 + l * 8];
          hacc[nf] = __builtin_amdgcn_mfma_f32_16x16x32_bf16(Ah, Bh, hacc[nf], 0, 0, 0);
          hacc[nf] = __builtin_amdgcn_mfma_f32_16x16x32_bf16(Ah, Bl, hacc[nf], 0, 0, 0);
          hacc[nf] = __builtin_amdgcn_mfma_f32_16x16x32_bf16(Al, Bh, hacc[nf], 0, 0, 0);
        }
      };
      hstage(0); hwrite(0);
      __syncthreads();
      for (int kc = 0; kc < 16; ++kc) {
        int buf = kc & 1;
        if (kc + 1 < 16) hstage(kc + 1);
        hcomp(buf);
        if (kc + 1 < 16) {
          __syncthreads();
          hwrite(buf ^ 1);
          __syncthreads();
        }
      }
      __syncthreads();
      float* GsF = (float*)Gs;
      int wm = w >> 1, wn = w & 1;
      #pragma unroll
      for (int nf = 0; nf < 2; ++nf)
        #pragma unroll
        for (int rq = 0; rq < 4; ++rq) {
          int rr = wm * 16 + (l >> 4) * 4 + rq;
          int ccl = wn * 32 + nf * 16 + (l & 15);
          GsF[rr * 64 + ccl] = geluf(hacc[nf][rq] + bias[hj0 + ccl]);
        }
      __syncthreads();
      if (yp) {
        // packed bf16 hi/lo fragment layout (consumable as next A)
        int chunk = tid >> 7, tt = tid & 127;
        int mf_loc = tt >> 6, lane = tt & 63;
        int row = mf_loc * 16 + (lane & 15);
        int kg = lane >> 4;
        S8 hi, lo;
        #pragma unroll
        for (int i = 0; i < 8; ++i) {
          float v = GsF[row * 64 + chunk * 32 + kg * 8 + i];
          us hh = f2bf(v);
          hi.v[i] = (short)hh;
          lo.v[i] = (short)f2bf(v - bf2f(hh));
        }
        us* dst = y1p + ((size_t)(mh >> 1) * 16 + (cb * 2 + chunk)) * 4096 + (mh & 1) * 2048;
        ast8(dst + (size_t)(mf_loc * 2 + 0) * 512 + lane * 8, hi.u[0]);
        ast8(dst + (size_t)(mf_loc * 2 + 0) * 512 + lane * 8 + 4, hi.u[1]);
        ast8(dst + (size_t)(mf_loc * 2 + 1) * 512 + lane * 8, lo.u[0]);
        ast8(dst + (size_t)(mf_loc * 2 + 1) * 512 + lane * 8 + 4, lo.u[1]);
      } else {
        int rr = tid >> 3, cc0 = (tid & 7) * 8;
        float* dst = yf + (size_t)(hrow0 + rr) * 512 + hj0 + cc0;
        #pragma unroll
        for (int i = 0; i < 4; ++i) {
          U8 p;
          p.f[0] = GsF[rr * 64 + cc0 + i * 2];
          p.f[1] = GsF[rr * 64 + cc0 + i * 2 + 1];
          ast8(dst + i * 2, p.u);
        }
      }
      __syncthreads();
    }
  };

  // ---------- fc3: all 256 WGs, 2 rows each ----------
  auto fc3p = [&](int kidx) {
    float* GsF = (float*)Gs;
    const float* src = y2 + (size_t)(bid * 2) * 512;
    U8 v0, v1;
    v0.u = ald8(src + tid * 4);
    v1.u = ald8(src + tid * 4 + 2);
    *(ull*)&GsF[tid * 4] = v0.u;
    *(ull*)&GsF[tid * 4 + 2] = v1.u;
    __syncthreads();
    int rloc = w >> 1, o = w & 1;
    float s = 0.f;
    #pragma unroll
    for (int i = 0; i < 8; ++i) {
      int idx = l + i * 64;
      s += GsF[rloc * 512 + idx] * fc3_w[o * 512 + idx];
    }
    #pragma unroll
    for (int d = 32; d > 0; d >>= 1) s += __shfl_down(s, d, 64);
    if (l == 0)
      __hip_atomic_store(out + (size_t)(bid * 2 + rloc) * OSTR + kidx * 2 + o,
                         s + fc3_b[o], __ATOMIC_RELAXED, __HIP_MEMORY_SCOPE_AGENT);
    __syncthreads();
  };

  // ================= schedule =================
  for (int t = 0; t < 64; ++t) { fused(t > 0, true, t, false, 0); gbar(); }
  fused(true, false, 64, false, 0); gbar();   // L1(63)

  for (int kidx = 0; kidx < 17; ++kidx) {
    const us* h1cur = ((63 + kidx) & 1) ? hp1_1 : hp1_0;
    headg(h1cur, Wpf1, fc1_b, nullptr, y1p); gbar();
    headg(y1p, Wpf2, fc2_b, y2, nullptr); gbar();
    fc3p(kidx);
    if (kidx < 16) {
      gbar();
      fused(false, true, 64 + kidx, true, kidx); gbar();
      fused(true, false, 65 + kidx, false, 0); gbar();
    }
  }
}

} // namespace

extern "C" void kernel_launch(void* const* d_in, const int* in_sizes, int n_in,
                              void* d_out, int out_size, void* d_ws, size_t ws_size,
                              hipStream_t stream) {
  const float* x     = (const float*)d_in[0];
  const float* w_ih0 = (const float*)d_in[1];
  const float* w_hh0 = (const float*)d_in[2];
  const float* b_ih0 = (const float*)d_in[3];
  const float* b_hh0 = (const float*)d_in[4];
  const float* w_ih1 = (const float*)d_in[5];
  const float* w_hh1 = (const float*)d_in[6];
  const float* b_ih1 = (const float*)d_in[7];
  const float* b_hh1 = (const float*)d_in[8];
  const float* fc1_w = (const float*)d_in[9];
  const float* fc1_b = (const float*)d_in[10];
  const float* fc2_w = (const float*)d_in[11];
  const float* fc2_b = (const float*)d_in[12];
  const float* fc3_w = (const float*)d_in[13];
  const float* fc3_b = (const float*)d_in[14];
  float* out = (float*)d_out;
  char* wsb = (char*)d_ws;

  constexpr size_t MB = 1048576;
  constexpr size_t O_WP0  = 0;                      // 32*17*8192 = 4456448
  constexpr size_t O_WP1  = 4456448;                // +8388608
  constexpr size_t O_WPF1 = O_WP1 + 8388608;        // +1048576
  constexpr size_t O_WPF2 = O_WPF1 + MB;            // +1048576
  constexpr size_t O_BS0  = O_WPF2 + MB;            // +8192
  constexpr size_t O_BS1  = O_BS0 + 8192;           // +8192
  constexpr size_t O_CNT  = O_BS1 + 8192;           // +4096
  constexpr size_t O_HP0B = O_CNT + 4096;           // hp0_1 (zeroed)
  constexpr size_t O_HP1B = O_HP0B + MB;            // hp1_1 (zeroed)
  constexpr size_t O_C0   = O_HP1B + MB;            // c0 (zeroed)
  constexpr size_t O_C1   = O_C0 + MB;              // c1 (zeroed)
  constexpr size_t O_HP0A = O_C1 + MB;              // hp0_0
  constexpr size_t O_HP1A = O_HP0A + MB;            // hp1_0
  constexpr size_t O_Y1P  = O_HP1A + MB;            // y1 packed (1MB)
  constexpr size_t O_Y2   = O_Y1P + MB;             // y2 f32 (1MB)

  us* Wp0  = (us*)(wsb + O_WP0);
  us* Wp1  = (us*)(wsb + O_WP1);
  us* Wpf1 = (us*)(wsb + O_WPF1);
  us* Wpf2 = (us*)(wsb + O_WPF2);
  float* bs0 = (float*)(wsb + O_BS0);
  float* bs1 = (float*)(wsb + O_BS1);
  int* cnt   = (int*)(wsb + O_CNT);
  us* hp0_1 = (us*)(wsb + O_HP0B);
  us* hp1_1 = (us*)(wsb + O_HP1B);
  float* c0 = (float*)(wsb + O_C0);
  float* c1 = (float*)(wsb + O_C1);
  us* hp0_0 = (us*)(wsb + O_HP0A);
  us* hp1_0 = (us*)(wsb + O_HP1A);
  us* y1p   = (us*)(wsb + O_Y1P);
  float* y2 = (float*)(wsb + O_Y2);

  pack_w_kernel<<<dim3(32 * 17), 256, 0, stream>>>(w_ih0, w_hh0, 32, 512, 17, 0, Wp0);
  pack_w_kernel<<<dim3(32 * 32), 256, 0, stream>>>(w_ih1, w_hh1, 512, 512, 32, 0, Wp1);
  pack_w_kernel<<<dim3(8 * 16), 256, 0, stream>>>(fc1_w, fc1_w, 512, 512, 16, 1, Wpf1);
  pack_w_kernel<<<dim3(8 * 16), 256, 0, stream>>>(fc2_w, fc2_w, 512, 512, 16, 1, Wpf2);
  bsum_kernel<<<dim3(16), 256, 0, stream>>>(b_ih0, b_hh0, b_ih1, b_hh1, bs0, bs1);
  // zero: cnt (4KB) + hp0_1,hp1_1,c0,c1 (4MB) — contiguous
  hipMemsetAsync(wsb + O_CNT, 0, 4096 + 4 * MB, stream);

  persist_kernel<<<dim3(256), dim3(256), 0, stream>>>(
      x, Wp0, Wp1, Wpf1, Wpf2, bs0, bs1, fc1_b, fc2_b, fc3_w, fc3_b,
      hp0_0, hp0_1, hp1_0, hp1_1, c0, c1, y1p, y2, out, cnt);
}

// Round 8
// 2727.165 us; speedup vs baseline: 2.6646x; 1.9137x over previous
//
#include <hip/hip_runtime.h>
#include <math.h>

typedef short s16x4 __attribute__((ext_vector_type(4)));
typedef short s16x8 __attribute__((ext_vector_type(8)));
typedef float f32x4 __attribute__((ext_vector_type(4)));
typedef unsigned short us;
typedef unsigned long long ull;

namespace {
constexpr int T = 80, Fdim = 32, H = 512, OSTR = 34;

__device__ __forceinline__ us f2bf(float f) {
  union { float f; unsigned u; } x; x.f = f;
  unsigned u = x.u; u += 0x7fffu + ((u >> 16) & 1u);
  return (us)(u >> 16);
}
__device__ __forceinline__ float bf2f(us s) {
  union { unsigned u; float f; } x; x.u = ((unsigned)s) << 16; return x.f;
}
__device__ __forceinline__ float sigf(float v) { return 1.f / (1.f + expf(-v)); }
__device__ __forceinline__ float geluf(float v) {
  return 0.5f * v * (1.f + erff(v * 0.70710678118654752f));
}

// device-coherent 8B data movement, compiler-managed (proven green in r7)
__device__ __forceinline__ ull ald8(const void* p) {
  return __hip_atomic_load((const ull*)p, __ATOMIC_RELAXED, __HIP_MEMORY_SCOPE_AGENT);
}
__device__ __forceinline__ void ast8(void* p, ull v) {
  __hip_atomic_store((ull*)p, v, __ATOMIC_RELAXED, __HIP_MEMORY_SCOPE_AGENT);
}

union U8 { ull u; s16x4 v4; float f[2]; };
union S8 { s16x8 v; ull u[2]; };

// ---------------- weight pre-pack ----------------
// block (8KB) idx = jb*NKC + kc: [strip(4)][half(2)][lane(64)][8 bf16]
__global__ __launch_bounds__(256)
void pack_w_kernel(const float* __restrict__ w1, const float* __restrict__ w2,
                   int K1, int K2, int NKC, int head, us* __restrict__ dst) {
  int bid = blockIdx.x;
  int jb = bid / NKC, kc = bid % NKC;
  int tid = threadIdx.x;
  int strip = tid >> 6, l = tid & 63;
  int nl = l & 15, kg = l >> 4;
  int n = head ? (jb * 64 + strip * 16 + nl) : (strip * 512 + jb * 16 + nl);
  s16x8 h8, l8;
  #pragma unroll
  for (int i = 0; i < 8; ++i) {
    int k = kc * 32 + kg * 8 + i;
    float v = (k < K1) ? w1[(size_t)n * K1 + k] : w2[(size_t)n * K2 + (k - K1)];
    us h = f2bf(v);
    h8[i] = (short)h;
    l8[i] = (short)f2bf(v - bf2f(h));
  }
  size_t base = (size_t)bid * 4096;
  *(s16x8*)&dst[base + (size_t)(strip * 2 + 0) * 512 + l * 8] = h8;
  *(s16x8*)&dst[base + (size_t)(strip * 2 + 1) * 512 + l * 8] = l8;
}

__global__ __launch_bounds__(256)
void bsum_kernel(const float* bi0, const float* bh0, const float* bi1, const float* bh1,
                 float* bs0, float* bs1) {
  int i = blockIdx.x * 256 + threadIdx.x;
  if (i < 2048) bs0[i] = bi0[i] + bh0[i];
  else { int j = i - 2048; bs1[j] = bi1[j] + bh1[j]; }
}

// ---------------- persistent whole-model kernel ----------------
__global__ __launch_bounds__(256, 1)
void persist_kernel(const float* __restrict__ x,
                    const us* __restrict__ Wp0, const us* __restrict__ Wp1,
                    const us* __restrict__ Wpf1, const us* __restrict__ Wpf2,
                    const float* __restrict__ bs0, const float* __restrict__ bs1,
                    const float* __restrict__ fc1_b, const float* __restrict__ fc2_b,
                    const float* __restrict__ fc3_w, const float* __restrict__ fc3_b,
                    us* hp0_0, us* hp0_1, us* hp1_0, us* hp1_1,
                    float* c0, float* c1, us* y1p, float* y2,
                    float* out, int* cnt)
{
  __shared__ __align__(16) us Ash[3][4096];
  __shared__ __align__(16) us Bsh[3][2][4096];
  __shared__ __align__(16) float Gs[4][64][16];

  const int tid = threadIdx.x;
  const int bid = blockIdx.x;
  const int w = tid >> 6, l = tid & 63;
  const int m = bid >> 5;                          // batch group 0..7 (64 rows)
  const int jb = (bid & 7) * 4 + ((bid >> 3) & 3); // group-local 0..31 (h-col slice)
  const int row0 = m * 64;
  const int j0 = jb * 16;
  const int base31 = j0 & 31;

  const us* WpJ0 = Wp0 + (size_t)jb * 17 * 4096;
  const us* WpJ1 = Wp1 + (size_t)jb * 32 * 4096;

  int ph = 0;
  // per-group barrier: 32 WGs sharing m. Groups are independent streams.
  auto gbar = [&]() {
    ++ph;
    __syncthreads();
    if (tid == 0) {
      __hip_atomic_fetch_add(&cnt[m * 64], 1, __ATOMIC_RELEASE,
                             __HIP_MEMORY_SCOPE_AGENT);
      while (__hip_atomic_load(&cnt[m * 64], __ATOMIC_RELAXED,
                               __HIP_MEMORY_SCOPE_AGENT) < 32 * ph)
        __builtin_amdgcn_s_sleep(1);
      __builtin_amdgcn_fence(__ATOMIC_ACQUIRE, "workgroup");
    }
    __syncthreads();
  };

  struct SetT { ull a0, a1, a2, a3; s16x8 b10, b11, b00, b01; };

  // ---------- fused LSTM phase: {L1(t-1) if DO1} + {L0(t) if DO0} ----------
  auto fused = [&](bool DO1, bool DO0, int t, bool use_fb, int kidx) {
    const us* h0prev = ((t + 1) & 1) ? hp0_1 : hp0_0;
    const us* h1prev = (t & 1) ? hp1_1 : hp1_0;
    us* h1w = ((t + 1) & 1) ? hp1_1 : hp1_0;
    us* h0w = (t & 1) ? hp0_1 : hp0_0;

    f32x4 acc0[4], acc1[4];
    #pragma unroll
    for (int mf = 0; mf < 4; ++mf) {
      acc0[mf] = {0.f, 0.f, 0.f, 0.f};
      acc1[mf] = {0.f, 0.f, 0.f, 0.f};
    }
    const int NP = DO1 ? 32 : 16;
    SetT R0, R1, R2, R3;

    auto iss = [&](int c, SetT& R) {
      if (c >= NP) return;
      const us* a = ((c < 16) ? h0prev : h1prev) + (size_t)(m * 16 + (c & 15)) * 4096;
      R.a0 = ald8(a + tid * 8);
      R.a1 = ald8(a + tid * 8 + 4);
      R.a2 = ald8(a + 2048 + tid * 8);
      R.a3 = ald8(a + 2048 + tid * 8 + 4);
      if (DO1) { const us* b = WpJ1 + (size_t)c * 4096;
                 R.b10 = *(const s16x8*)(b + tid * 8);
                 R.b11 = *(const s16x8*)(b + 2048 + tid * 8); }
      if (DO0 && c < 16) { const us* b = WpJ0 + (size_t)(c + 1) * 4096;
                           R.b00 = *(const s16x8*)(b + tid * 8);
                           R.b01 = *(const s16x8*)(b + 2048 + tid * 8); }
    };
    auto wrt = [&](int c, SetT& R) {
      if (c >= NP) return;
      int sl = c % 3;
      *(ull*)&Ash[sl][tid * 8] = R.a0;
      *(ull*)&Ash[sl][tid * 8 + 4] = R.a1;
      *(ull*)&Ash[sl][2048 + tid * 8] = R.a2;
      *(ull*)&Ash[sl][2048 + tid * 8 + 4] = R.a3;
      if (DO1) { *(s16x8*)&Bsh[sl][0][tid * 8] = R.b10;
                 *(s16x8*)&Bsh[sl][0][2048 + tid * 8] = R.b11; }
      if (DO0 && c < 16) { *(s16x8*)&Bsh[sl][1][tid * 8] = R.b00;
                           *(s16x8*)&Bsh[sl][1][2048 + tid * 8] = R.b01; }
    };
    auto lcomp = [&](int sl, bool c1on, bool c0on) {
      s16x8 B1h, B1l, B0h, B0l;
      if (c1on) { B1h = *(const s16x8*)&Bsh[sl][0][(w * 2 + 0) * 512 + l * 8];
                  B1l = *(const s16x8*)&Bsh[sl][0][(w * 2 + 1) * 512 + l * 8]; }
      if (c0on) { B0h = *(const s16x8*)&Bsh[sl][1][(w * 2 + 0) * 512 + l * 8];
                  B0l = *(const s16x8*)&Bsh[sl][1][(w * 2 + 1) * 512 + l * 8]; }
      #pragma unroll
      for (int mf = 0; mf < 4; ++mf) {
        s16x8 Ah = *(const s16x8*)&Ash[sl][(mf * 2 + 0) * 512 + l * 8];
        s16x8 Al = *(const s16x8*)&Ash[sl][(mf * 2 + 1) * 512 + l * 8];
        if (c1on) {
          acc1[mf] = __builtin_amdgcn_mfma_f32_16x16x32_bf16(Ah, B1h, acc1[mf], 0, 0, 0);
          acc1[mf] = __builtin_amdgcn_mfma_f32_16x16x32_bf16(Ah, B1l, acc1[mf], 0, 0, 0);
          acc1[mf] = __builtin_amdgcn_mfma_f32_16x16x32_bf16(Al, B1h, acc1[mf], 0, 0, 0);
        }
        if (c0on) {
          acc0[mf] = __builtin_amdgcn_mfma_f32_16x16x32_bf16(Ah, B0h, acc0[mf], 0, 0, 0);
          acc0[mf] = __builtin_amdgcn_mfma_f32_16x16x32_bf16(Ah, B0l, acc0[mf], 0, 0, 0);
          acc0[mf] = __builtin_amdgcn_mfma_f32_16x16x32_bf16(Al, B0h, acc0[mf], 0, 0, 0);
        }
      }
    };

    // prologue: chunks 0..5 in flight (depth 4 sustained)
    iss(0, R0); iss(1, R1); iss(2, R2); iss(3, R3);
    wrt(0, R0); iss(4, R0);
    wrt(1, R1); iss(5, R1);
    __syncthreads();
    // steady state: iter kc: compute kc | LDS-write kc+2 | issue kc+6 | 1 sync
    for (int base = 0; base < NP; base += 4) {
      { int kc = base + 0; lcomp(kc % 3, DO1, DO0 && kc < 16);
        wrt(kc + 2, R2); iss(kc + 6, R2); __syncthreads(); }
      { int kc = base + 1; lcomp(kc % 3, DO1, DO0 && kc < 16);
        wrt(kc + 2, R3); iss(kc + 6, R3); __syncthreads(); }
      { int kc = base + 2; lcomp(kc % 3, DO1, DO0 && kc < 16);
        wrt(kc + 2, R0); iss(kc + 6, R0); __syncthreads(); }
      { int kc = base + 3; lcomp(kc % 3, DO1, DO0 && kc < 16);
        wrt(kc + 2, R1); iss(kc + 6, R1); __syncthreads(); }
    }

    if (DO0) {  // x chunk (L0 weight chunk 0) — all slots free after loop
      *(s16x8*)&Bsh[0][1][tid * 8] = *(const s16x8*)(WpJ0 + tid * 8);
      *(s16x8*)&Bsh[0][1][2048 + tid * 8] = *(const s16x8*)(WpJ0 + 2048 + tid * 8);
      int srow = tid >> 2, skg = tid & 3;
      const float* xp = x + (size_t)(row0 + srow) * (T * Fdim) + (size_t)t * Fdim + skg * 8;
      float v[8];
      #pragma unroll
      for (int i = 0; i < 8; ++i) v[i] = xp[i];
      if (use_fb && skg == 0) {
        const float* op = out + (size_t)(row0 + srow) * OSTR + kidx * 2;
        v[4] = __hip_atomic_load(op, __ATOMIC_RELAXED, __HIP_MEMORY_SCOPE_AGENT);
        v[5] = __hip_atomic_load(op + 1, __ATOMIC_RELAXED, __HIP_MEMORY_SCOPE_AGENT);
      }
      s16x8 h8, l8;
      #pragma unroll
      for (int i = 0; i < 8; ++i) {
        us hh = f2bf(v[i]);
        h8[i] = (short)hh;
        l8[i] = (short)f2bf(v[i] - bf2f(hh));
      }
      int slane = skg * 16 + (srow & 15), smf = srow >> 4;
      *(s16x8*)&Ash[0][(smf * 2 + 0) * 512 + slane * 8] = h8;
      *(s16x8*)&Ash[0][(smf * 2 + 1) * 512 + slane * 8] = l8;
      __syncthreads();
      lcomp(0, false, true);
    }

    // epilogue: stash gates -> cell -> packed coherent h write
    auto epi = [&](f32x4* acc, const float* bsum, float* cst, us* hw) {
      __syncthreads();
      float bsv = bsum[w * 512 + j0 + (l & 15)];
      #pragma unroll
      for (int mf = 0; mf < 4; ++mf)
        #pragma unroll
        for (int r = 0; r < 4; ++r)
          Gs[w][mf * 16 + (l >> 4) * 4 + r][l & 15] = acc[mf][r] + bsv;
      __syncthreads();
      int r = tid >> 2, sub = tid & 3, cc0 = sub * 4;
      float gvi[4], gvf[4], gvg[4], gvo[4], cv[4], cn[4], hv[4];
      #pragma unroll
      for (int q = 0; q < 4; ++q) {
        gvi[q] = Gs[0][r][cc0 + q]; gvf[q] = Gs[1][r][cc0 + q];
        gvg[q] = Gs[2][r][cc0 + q]; gvo[q] = Gs[3][r][cc0 + q];
      }
      size_t cix = (size_t)(row0 + r) * H + j0 + cc0;
      float4 cold = *(const float4*)&cst[cix];
      cv[0] = cold.x; cv[1] = cold.y; cv[2] = cold.z; cv[3] = cold.w;
      #pragma unroll
      for (int q = 0; q < 4; ++q) {
        float c2 = sigf(gvf[q]) * cv[q] + sigf(gvi[q]) * tanhf(gvg[q]);
        cn[q] = c2;
        hv[q] = sigf(gvo[q]) * tanhf(c2);
      }
      *(float4*)&cst[cix] = make_float4(cn[0], cn[1], cn[2], cn[3]);
      int kk = base31 + cc0;
      int kg = kk >> 3, i0 = kk & 7;
      int mf = r >> 4;
      int lane2 = kg * 16 + (r & 15);
      us* bb = hw + (size_t)(m * 16 + (j0 >> 5)) * 4096;
      U8 hh, hl;
      #pragma unroll
      for (int q = 0; q < 4; ++q) {
        us h2 = f2bf(hv[q]);
        hh.v4[q] = (short)h2;
        hl.v4[q] = (short)f2bf(hv[q] - bf2f(h2));
      }
      ast8(bb + (size_t)(mf * 2 + 0) * 512 + lane2 * 8 + i0, hh.u);
      ast8(bb + (size_t)(mf * 2 + 1) * 512 + lane2 * 8 + i0, hl.u);
      __syncthreads();
    };
    if (DO1) epi(acc1, bs1, c1, h1w);
    if (DO0) epi(acc0, bs0, c0, h0w);
  };

  // ---------- head GEMM: group-local, 16 of 32 WGs, 32 rows x 64 cols ----------
  struct HSet { ull a0, a1; s16x8 b0, b1; };
  auto headg = [&](const us* apack, const us* Wp, const float* bias,
                   float* yf, us* yp) {
    if (jb < 16) {
      const int mh = m * 2 + (jb >> 3), cb = jb & 7;
      const int hrow0 = mh * 32, hj0 = cb * 64;
      f32x4 hacc[2];
      hacc[0] = {0.f, 0.f, 0.f, 0.f};
      hacc[1] = {0.f, 0.f, 0.f, 0.f};
      HSet H0, H1, H2, H3;
      auto hiss = [&](int c, HSet& R) {
        if (c >= 16) return;
        const us* a = apack + (size_t)(m * 16 + c) * 4096 + (mh & 1) * 2048;
        R.a0 = ald8(a + tid * 8);
        R.a1 = ald8(a + tid * 8 + 4);
        const us* b = Wp + (size_t)(cb * 16 + c) * 4096;
        R.b0 = *(const s16x8*)(b + tid * 8);
        R.b1 = *(const s16x8*)(b + 2048 + tid * 8);
      };
      auto hwrt = [&](int c, HSet& R) {
        if (c >= 16) return;
        int sl = c % 3;
        *(ull*)&Ash[sl][tid * 8] = R.a0;
        *(ull*)&Ash[sl][tid * 8 + 4] = R.a1;
        *(s16x8*)&Bsh[sl][0][tid * 8] = R.b0;
        *(s16x8*)&Bsh[sl][0][2048 + tid * 8] = R.b1;
      };
      auto hcmp = [&](int sl) {
        int wm = w >> 1, wn = w & 1;
        s16x8 Ah = *(const s16x8*)&Ash[sl][(wm * 2 + 0) * 512 + l * 8];
        s16x8 Al = *(const s16x8*)&Ash[sl][(wm * 2 + 1) * 512 + l * 8];
        #pragma unroll
        for (int nf = 0; nf < 2; ++nf) {
          s16x8 Bh = *(const s16x8*)&Bsh[sl][0][((wn * 2 + nf) * 2 + 0) * 512 + l * 8];
          s16x8 Bl = *(const s16x8*)&Bsh[sl][0][((wn * 2 + nf) * 2 + 1) * 512 + l * 8];
          hacc[nf] = __builtin_amdgcn_mfma_f32_16x16x32_bf16(Ah, Bh, hacc[nf], 0, 0, 0);
          hacc[nf] = __builtin_amdgcn_mfma_f32_16x16x32_bf16(Ah, Bl, hacc[nf], 0, 0, 0);
          hacc[nf] = __builtin_amdgcn_mfma_f32_16x16x32_bf16(Al, Bh, hacc[nf], 0, 0, 0);
        }
      };
      hiss(0, H0); hiss(1, H1); hiss(2, H2); hiss(3, H3);
      hwrt(0, H0); hiss(4, H0);
      hwrt(1, H1); hiss(5, H1);
      __syncthreads();
      for (int base = 0; base < 16; base += 4) {
        { int kc = base + 0; hcmp(kc % 3); hwrt(kc + 2, H2); hiss(kc + 6, H2); __syncthreads(); }
        { int kc = base + 1; hcmp(kc % 3); hwrt(kc + 2, H3); hiss(kc + 6, H3); __syncthreads(); }
        { int kc = base + 2; hcmp(kc % 3); hwrt(kc + 2, H0); hiss(kc + 6, H0); __syncthreads(); }
        { int kc = base + 3; hcmp(kc % 3); hwrt(kc + 2, H1); hiss(kc + 6, H1); __syncthreads(); }
      }
      __syncthreads();
      float* GsF = (float*)Gs;
      int wm = w >> 1, wn = w & 1;
      #pragma unroll
      for (int nf = 0; nf < 2; ++nf)
        #pragma unroll
        for (int rq = 0; rq < 4; ++rq) {
          int rr = wm * 16 + (l >> 4) * 4 + rq;
          int ccl = wn * 32 + nf * 16 + (l & 15);
          GsF[rr * 64 + ccl] = geluf(hacc[nf][rq] + bias[hj0 + ccl]);
        }
      __syncthreads();
      if (yp) {
        // packed bf16 hi/lo fragment layout (consumable as next A)
        int chunk = tid >> 7, tt = tid & 127;
        int mf_loc = tt >> 6, lane = tt & 63;
        int row = mf_loc * 16 + (lane & 15);
        int kg = lane >> 4;
        S8 hi, lo;
        #pragma unroll
        for (int i = 0; i < 8; ++i) {
          float v = GsF[row * 64 + chunk * 32 + kg * 8 + i];
          us hh = f2bf(v);
          hi.v[i] = (short)hh;
          lo.v[i] = (short)f2bf(v - bf2f(hh));
        }
        us* dst = yp + ((size_t)m * 16 + (cb * 2 + chunk)) * 4096 + (mh & 1) * 2048;
        ast8(dst + (size_t)(mf_loc * 2 + 0) * 512 + lane * 8, hi.u[0]);
        ast8(dst + (size_t)(mf_loc * 2 + 0) * 512 + lane * 8 + 4, hi.u[1]);
        ast8(dst + (size_t)(mf_loc * 2 + 1) * 512 + lane * 8, lo.u[0]);
        ast8(dst + (size_t)(mf_loc * 2 + 1) * 512 + lane * 8 + 4, lo.u[1]);
      } else {
        int rr = tid >> 3, cc0 = (tid & 7) * 8;
        float* dst = yf + (size_t)(hrow0 + rr) * 512 + hj0 + cc0;
        #pragma unroll
        for (int i = 0; i < 4; ++i) {
          U8 p;
          p.f[0] = GsF[rr * 64 + cc0 + i * 2];
          p.f[1] = GsF[rr * 64 + cc0 + i * 2 + 1];
          ast8(dst + i * 2, p.u);
        }
      }
      __syncthreads();
    }
  };

  // ---------- fc3: group-local, 2 rows per WG ----------
  auto fc3p = [&](int kidx) {
    float* GsF = (float*)Gs;
    int r0 = m * 64 + jb * 2;
    const float* src = y2 + (size_t)r0 * 512;
    U8 v0, v1;
    v0.u = ald8(src + tid * 4);
    v1.u = ald8(src + tid * 4 + 2);
    *(ull*)&GsF[tid * 4] = v0.u;
    *(ull*)&GsF[tid * 4 + 2] = v1.u;
    __syncthreads();
    int rloc = w >> 1, o = w & 1;
    float s = 0.f;
    #pragma unroll
    for (int i = 0; i < 8; ++i) {
      int idx = l + i * 64;
      s += GsF[rloc * 512 + idx] * fc3_w[o * 512 + idx];
    }
    #pragma unroll
    for (int d = 32; d > 0; d >>= 1) s += __shfl_down(s, d, 64);
    if (l == 0)
      __hip_atomic_store(out + (size_t)(r0 + rloc) * OSTR + kidx * 2 + o,
                         s + fc3_b[o], __ATOMIC_RELAXED, __HIP_MEMORY_SCOPE_AGENT);
    __syncthreads();
  };

  // ================= schedule (each m-group runs independently) =================
  for (int t = 0; t < 64; ++t) { fused(t > 0, true, t, false, 0); gbar(); }
  fused(true, false, 64, false, 0); gbar();   // L1(63)

  for (int kidx = 0; kidx < 17; ++kidx) {
    const us* h1cur = ((63 + kidx) & 1) ? hp1_1 : hp1_0;
    headg(h1cur, Wpf1, fc1_b, nullptr, y1p); gbar();
    headg(y1p, Wpf2, fc2_b, y2, nullptr); gbar();
    fc3p(kidx);
    if (kidx < 16) {
      gbar();
      fused(false, true, 64 + kidx, true, kidx); gbar();
      fused(true, false, 65 + kidx, false, 0); gbar();
    }
  }
}

} // namespace

extern "C" void kernel_launch(void* const* d_in, const int* in_sizes, int n_in,
                              void* d_out, int out_size, void* d_ws, size_t ws_size,
                              hipStream_t stream) {
  const float* x     = (const float*)d_in[0];
  const float* w_ih0 = (const float*)d_in[1];
  const float* w_hh0 = (const float*)d_in[2];
  const float* b_ih0 = (const float*)d_in[3];
  const float* b_hh0 = (const float*)d_in[4];
  const float* w_ih1 = (const float*)d_in[5];
  const float* w_hh1 = (const float*)d_in[6];
  const float* b_ih1 = (const float*)d_in[7];
  const float* b_hh1 = (const float*)d_in[8];
  const float* fc1_w = (const float*)d_in[9];
  const float* fc1_b = (const float*)d_in[10];
  const float* fc2_w = (const float*)d_in[11];
  const float* fc2_b = (const float*)d_in[12];
  const float* fc3_w = (const float*)d_in[13];
  const float* fc3_b = (const float*)d_in[14];
  float* out = (float*)d_out;
  char* wsb = (char*)d_ws;

  constexpr size_t MB = 1048576;
  constexpr size_t O_WP0  = 0;                      // 32*17*8192 = 4456448
  constexpr size_t O_WP1  = 4456448;                // +8388608
  constexpr size_t O_WPF1 = O_WP1 + 8388608;        // +1048576
  constexpr size_t O_WPF2 = O_WPF1 + MB;            // +1048576
  constexpr size_t O_BS0  = O_WPF2 + MB;            // +8192
  constexpr size_t O_BS1  = O_BS0 + 8192;           // +8192
  constexpr size_t O_CNT  = O_BS1 + 8192;           // +4096
  constexpr size_t O_HP0B = O_CNT + 4096;           // hp0_1 (zeroed)
  constexpr size_t O_HP1B = O_HP0B + MB;            // hp1_1 (zeroed)
  constexpr size_t O_C0   = O_HP1B + MB;            // c0 (zeroed)
  constexpr size_t O_C1   = O_C0 + MB;              // c1 (zeroed)
  constexpr size_t O_HP0A = O_C1 + MB;              // hp0_0
  constexpr size_t O_HP1A = O_HP0A + MB;            // hp1_0
  constexpr size_t O_Y1P  = O_HP1A + MB;            // y1 packed (1MB)
  constexpr size_t O_Y2   = O_Y1P + MB;             // y2 f32 (1MB)

  us* Wp0  = (us*)(wsb + O_WP0);
  us* Wp1  = (us*)(wsb + O_WP1);
  us* Wpf1 = (us*)(wsb + O_WPF1);
  us* Wpf2 = (us*)(wsb + O_WPF2);
  float* bs0 = (float*)(wsb + O_BS0);
  float* bs1 = (float*)(wsb + O_BS1);
  int* cnt   = (int*)(wsb + O_CNT);
  us* hp0_1 = (us*)(wsb + O_HP0B);
  us* hp1_1 = (us*)(wsb + O_HP1B);
  float* c0 = (float*)(wsb + O_C0);
  float* c1 = (float*)(wsb + O_C1);
  us* hp0_0 = (us*)(wsb + O_HP0A);
  us* hp1_0 = (us*)(wsb + O_HP1A);
  us* y1p   = (us*)(wsb + O_Y1P);
  float* y2 = (float*)(wsb + O_Y2);

  pack_w_kernel<<<dim3(32 * 17), 256, 0, stream>>>(w_ih0, w_hh0, 32, 512, 17, 0, Wp0);
  pack_w_kernel<<<dim3(32 * 32), 256, 0, stream>>>(w_ih1, w_hh1, 512, 512, 32, 0, Wp1);
  pack_w_kernel<<<dim3(8 * 16), 256, 0, stream>>>(fc1_w, fc1_w, 512, 512, 16, 1, Wpf1);
  pack_w_kernel<<<dim3(8 * 16), 256, 0, stream>>>(fc2_w, fc2_w, 512, 512, 16, 1, Wpf2);
  bsum_kernel<<<dim3(16), 256, 0, stream>>>(b_ih0, b_hh0, b_ih1, b_hh1, bs0, bs1);
  // zero: cnt (4KB) + hp0_1,hp1_1,c0,c1 (4MB) — contiguous
  hipMemsetAsync(wsb + O_CNT, 0, 4096 + 4 * MB, stream);

  persist_kernel<<<dim3(256), dim3(256), 0, stream>>>(
      x, Wp0, Wp1, Wpf1, Wpf2, bs0, bs1, fc1_b, fc2_b, fc3_w, fc3_b,
      hp0_0, hp0_1, hp1_0, hp1_1, c0, c1, y1p, y2, out, cnt);
}

// Round 11
// 2601.327 us; speedup vs baseline: 2.7935x; 1.0484x over previous
//
#include <hip/hip_runtime.h>
#include <math.h>

typedef short s16x4 __attribute__((ext_vector_type(4)));
typedef short s16x8 __attribute__((ext_vector_type(8)));
typedef float f32x4 __attribute__((ext_vector_type(4)));
typedef unsigned short us;
typedef unsigned long long ull;

#define WAITVM(N) do { asm volatile("s_waitcnt vmcnt(" #N ")" ::: "memory"); __builtin_amdgcn_sched_barrier(0); } while (0)

namespace {
constexpr int T = 80, Fdim = 32, H = 512, OSTR = 34;

__device__ __forceinline__ us f2bf(float f) {
  union { float f; unsigned u; } x; x.f = f;
  unsigned u = x.u; u += 0x7fffu + ((u >> 16) & 1u);
  return (us)(u >> 16);
}
__device__ __forceinline__ float bf2f(us s) {
  union { unsigned u; float f; } x; x.u = ((unsigned)s) << 16; return x.f;
}
__device__ __forceinline__ float sigf(float v) { return 1.f / (1.f + expf(-v)); }
__device__ __forceinline__ float geluf(float v) {
  return 0.5f * v * (1.f + erff(v * 0.70710678118654752f));
}

// device-coherent 8B data movement, compiler-managed (proven green r7/r8)
__device__ __forceinline__ ull ald8(const void* p) {
  return __hip_atomic_load((const ull*)p, __ATOMIC_RELAXED, __HIP_MEMORY_SCOPE_AGENT);
}
__device__ __forceinline__ void ast8(void* p, ull v) {
  __hip_atomic_store((ull*)p, v, __ATOMIC_RELAXED, __HIP_MEMORY_SCOPE_AGENT);
}

union U8 { ull u; s16x4 v4; float f[2]; };
union S8 { s16x8 v; ull u[2]; };

// ---------------- weight pre-pack (unchanged) ----------------
__global__ __launch_bounds__(256)
void pack_w_kernel(const float* __restrict__ w1, const float* __restrict__ w2,
                   int K1, int K2, int NKC, int head, us* __restrict__ dst) {
  int bid = blockIdx.x;
  int jb = bid / NKC, kc = bid % NKC;
  int tid = threadIdx.x;
  int strip = tid >> 6, l = tid & 63;
  int nl = l & 15, kg = l >> 4;
  int n = head ? (jb * 64 + strip * 16 + nl) : (strip * 512 + jb * 16 + nl);
  s16x8 h8, l8;
  #pragma unroll
  for (int i = 0; i < 8; ++i) {
    int k = kc * 32 + kg * 8 + i;
    float v = (k < K1) ? w1[(size_t)n * K1 + k] : w2[(size_t)n * K2 + (k - K1)];
    us h = f2bf(v);
    h8[i] = (short)h;
    l8[i] = (short)f2bf(v - bf2f(h));
  }
  size_t base = (size_t)bid * 4096;
  *(s16x8*)&dst[base + (size_t)(strip * 2 + 0) * 512 + l * 8] = h8;
  *(s16x8*)&dst[base + (size_t)(strip * 2 + 1) * 512 + l * 8] = l8;
}

__global__ __launch_bounds__(256)
void bsum_kernel(const float* bi0, const float* bh0, const float* bi1, const float* bh1,
                 float* bs0, float* bs1) {
  int i = blockIdx.x * 256 + threadIdx.x;
  if (i < 2048) bs0[i] = bi0[i] + bh0[i];
  else { int j = i - 2048; bs1[j] = bi1[j] + bh1[j]; }
}

// ---------------- persistent whole-model kernel ----------------
// 256 WGs = 8 independent groups (64 batch rows each) x 32 WGs (16 h-cols each).
__global__ __launch_bounds__(256, 1)
void persist_kernel(const float* __restrict__ x,
                    const us* __restrict__ Wp0, const us* __restrict__ Wp1,
                    const us* __restrict__ Wpf1, const us* __restrict__ Wpf2,
                    const float* __restrict__ bs0, const float* __restrict__ bs1,
                    const float* __restrict__ fc1_b, const float* __restrict__ fc2_b,
                    const float* __restrict__ fc3_w, const float* __restrict__ fc3_b,
                    us* hp0_0, us* hp0_1, us* hp1_0, us* hp1_1,
                    float* c0, float* c1, us* y1p, float* y2,
                    float* out, int* cnt)
{
  __shared__ __align__(16) us Ash[3][4096];
  __shared__ __align__(16) us Bsh[3][2][4096];
  __shared__ __align__(16) float Gs[4][64][16];

  const int tid = threadIdx.x;
  const int bid = blockIdx.x;
  const int w = tid >> 6, l = tid & 63;
  const int m = bid >> 5;                      // group 0..7 (64 rows)
  const int lb = bid & 31;                     // group-local WG id
  const int jb = (lb & 7) * 4 + (lb >> 3);     // h-col slice 0..31
  const int row0 = m * 64;
  const int j0 = jb * 16;
  const int base31 = j0 & 31;

  const us* WpJ0 = Wp0 + (size_t)jb * 17 * 4096;
  const us* WpJ1 = Wp1 + (size_t)jb * 32 * 4096;

  int ph = 0;
  // per-group barrier: 32 WGs sharing m; explicit vmcnt drain first (r7 pattern)
  auto gbar = [&]() {
    ++ph;
    WAITVM(0);
    __syncthreads();
    if (tid == 0) {
      __hip_atomic_fetch_add(&cnt[m * 64], 1, __ATOMIC_RELEASE,
                             __HIP_MEMORY_SCOPE_AGENT);
      while (__hip_atomic_load(&cnt[m * 64], __ATOMIC_RELAXED,
                               __HIP_MEMORY_SCOPE_AGENT) < 32 * ph)
        __builtin_amdgcn_s_sleep(1);
      __builtin_amdgcn_fence(__ATOMIC_ACQUIRE, "workgroup");
    }
    __syncthreads();
  };

  struct SetT { ull a0, a1, a2, a3; s16x8 b10, b11, b00, b01; };

  // ---------- fused LSTM phase: {L1(t-1) if DO1} + {L0(t) if DO0} ----------
  auto fused = [&](bool DO1, bool DO0, int t, bool use_fb, int kidx) {
    const us* h0prev = ((t + 1) & 1) ? hp0_1 : hp0_0;
    const us* h1prev = (t & 1) ? hp1_1 : hp1_0;
    us* h1w = ((t + 1) & 1) ? hp1_1 : hp1_0;
    us* h0w = (t & 1) ? hp0_1 : hp0_0;

    f32x4 acc0[4], acc1[4];
    #pragma unroll
    for (int mf = 0; mf < 4; ++mf) {
      acc0[mf] = {0.f, 0.f, 0.f, 0.f};
      acc1[mf] = {0.f, 0.f, 0.f, 0.f};
    }
    const int NP = DO1 ? 32 : 16;
    SetT R0, R1, R2, R3;

    auto iss = [&](int c, SetT& R) {
      if (c >= NP) return;
      const us* a = ((c < 16) ? h0prev : h1prev) + (size_t)(m * 16 + (c & 15)) * 4096;
      R.a0 = ald8(a + tid * 8);
      R.a1 = ald8(a + tid * 8 + 4);
      R.a2 = ald8(a + 2048 + tid * 8);
      R.a3 = ald8(a + 2048 + tid * 8 + 4);
      if (DO1) { const us* b = WpJ1 + (size_t)c * 4096;
                 R.b10 = *(const s16x8*)(b + tid * 8);
                 R.b11 = *(const s16x8*)(b + 2048 + tid * 8); }
      if (DO0 && c < 16) { const us* b = WpJ0 + (size_t)(c + 1) * 4096;
                           R.b00 = *(const s16x8*)(b + tid * 8);
                           R.b01 = *(const s16x8*)(b + 2048 + tid * 8); }
    };
    auto wrt = [&](int c, SetT& R) {
      if (c >= NP) return;
      int sl = c % 3;
      *(ull*)&Ash[sl][tid * 8] = R.a0;
      *(ull*)&Ash[sl][tid * 8 + 4] = R.a1;
      *(ull*)&Ash[sl][2048 + tid * 8] = R.a2;
      *(ull*)&Ash[sl][2048 + tid * 8 + 4] = R.a3;
      if (DO1) { *(s16x8*)&Bsh[sl][0][tid * 8] = R.b10;
                 *(s16x8*)&Bsh[sl][0][2048 + tid * 8] = R.b11; }
      if (DO0 && c < 16) { *(s16x8*)&Bsh[sl][1][tid * 8] = R.b00;
                           *(s16x8*)&Bsh[sl][1][2048 + tid * 8] = R.b01; }
    };
    auto lcomp = [&](int sl, bool c1on, bool c0on) {
      s16x8 B1h, B1l, B0h, B0l;
      if (c1on) { B1h = *(const s16x8*)&Bsh[sl][0][(w * 2 + 0) * 512 + l * 8];
                  B1l = *(const s16x8*)&Bsh[sl][0][(w * 2 + 1) * 512 + l * 8]; }
      if (c0on) { B0h = *(const s16x8*)&Bsh[sl][1][(w * 2 + 0) * 512 + l * 8];
                  B0l = *(const s16x8*)&Bsh[sl][1][(w * 2 + 1) * 512 + l * 8]; }
      #pragma unroll
      for (int mf = 0; mf < 4; ++mf) {
        s16x8 Ah = *(const s16x8*)&Ash[sl][(mf * 2 + 0) * 512 + l * 8];
        s16x8 Al = *(const s16x8*)&Ash[sl][(mf * 2 + 1) * 512 + l * 8];
        if (c1on) {
          acc1[mf] = __builtin_amdgcn_mfma_f32_16x16x32_bf16(Ah, B1h, acc1[mf], 0, 0, 0);
          acc1[mf] = __builtin_amdgcn_mfma_f32_16x16x32_bf16(Ah, B1l, acc1[mf], 0, 0, 0);
          acc1[mf] = __builtin_amdgcn_mfma_f32_16x16x32_bf16(Al, B1h, acc1[mf], 0, 0, 0);
        }
        if (c0on) {
          acc0[mf] = __builtin_amdgcn_mfma_f32_16x16x32_bf16(Ah, B0h, acc0[mf], 0, 0, 0);
          acc0[mf] = __builtin_amdgcn_mfma_f32_16x16x32_bf16(Ah, B0l, acc0[mf], 0, 0, 0);
          acc0[mf] = __builtin_amdgcn_mfma_f32_16x16x32_bf16(Al, B0h, acc0[mf], 0, 0, 0);
        }
      }
    };

    // prologue: depth-4, period-4 register rotation (proven green in r8)
    iss(0, R0); iss(1, R1); iss(2, R2); iss(3, R3);
    wrt(0, R0); iss(4, R0);
    wrt(1, R1); iss(5, R1);
    __syncthreads();
    for (int base = 0; base < NP; base += 4) {
      { int kc = base + 0; lcomp(kc % 3, DO1, DO0 && kc < 16);
        wrt(kc + 2, R2); iss(kc + 6, R2); __syncthreads(); }
      { int kc = base + 1; lcomp(kc % 3, DO1, DO0 && kc < 16);
        wrt(kc + 2, R3); iss(kc + 6, R3); __syncthreads(); }
      { int kc = base + 2; lcomp(kc % 3, DO1, DO0 && kc < 16);
        wrt(kc + 2, R0); iss(kc + 6, R0); __syncthreads(); }
      { int kc = base + 3; lcomp(kc % 3, DO1, DO0 && kc < 16);
        wrt(kc + 2, R1); iss(kc + 6, R1); __syncthreads(); }
    }

    if (DO0) {  // x chunk (L0 weight chunk 0)
      *(s16x8*)&Bsh[0][1][tid * 8] = *(const s16x8*)(WpJ0 + tid * 8);
      *(s16x8*)&Bsh[0][1][2048 + tid * 8] = *(const s16x8*)(WpJ0 + 2048 + tid * 8);
      int srow = tid >> 2, skg = tid & 3;
      const float* xp = x + (size_t)(row0 + srow) * (T * Fdim) + (size_t)t * Fdim + skg * 8;
      float v[8];
      #pragma unroll
      for (int i = 0; i < 8; ++i) v[i] = xp[i];
      if (use_fb && skg == 0) {
        const float* op = out + (size_t)(row0 + srow) * OSTR + kidx * 2;
        v[4] = __hip_atomic_load(op, __ATOMIC_RELAXED, __HIP_MEMORY_SCOPE_AGENT);
        v[5] = __hip_atomic_load(op + 1, __ATOMIC_RELAXED, __HIP_MEMORY_SCOPE_AGENT);
      }
      s16x8 h8, l8;
      #pragma unroll
      for (int i = 0; i < 8; ++i) {
        us hh = f2bf(v[i]);
        h8[i] = (short)hh;
        l8[i] = (short)f2bf(v[i] - bf2f(hh));
      }
      int slane = skg * 16 + (srow & 15), smf = srow >> 4;
      *(s16x8*)&Ash[0][(smf * 2 + 0) * 512 + slane * 8] = h8;
      *(s16x8*)&Ash[0][(smf * 2 + 1) * 512 + slane * 8] = l8;
      __syncthreads();
      lcomp(0, false, true);
    }

    // epilogue: stash gates -> cell -> packed coherent h write
    auto epi = [&](f32x4* acc, const float* bsum, float* cst, us* hw) {
      __syncthreads();
      float bsv = bsum[w * 512 + j0 + (l & 15)];
      #pragma unroll
      for (int mf = 0; mf < 4; ++mf)
        #pragma unroll
        for (int r = 0; r < 4; ++r)
          Gs[w][mf * 16 + (l >> 4) * 4 + r][l & 15] = acc[mf][r] + bsv;
      __syncthreads();
      int r = tid >> 2, sub = tid & 3, cc0 = sub * 4;
      float gvi[4], gvf[4], gvg[4], gvo[4], cv[4], cn[4], hv[4];
      #pragma unroll
      for (int q = 0; q < 4; ++q) {
        gvi[q] = Gs[0][r][cc0 + q]; gvf[q] = Gs[1][r][cc0 + q];
        gvg[q] = Gs[2][r][cc0 + q]; gvo[q] = Gs[3][r][cc0 + q];
      }
      size_t cix = (size_t)(row0 + r) * H + j0 + cc0;
      float4 cold = *(const float4*)&cst[cix];
      cv[0] = cold.x; cv[1] = cold.y; cv[2] = cold.z; cv[3] = cold.w;
      #pragma unroll
      for (int q = 0; q < 4; ++q) {
        float c2 = sigf(gvf[q]) * cv[q] + sigf(gvi[q]) * tanhf(gvg[q]);
        cn[q] = c2;
        hv[q] = sigf(gvo[q]) * tanhf(c2);
      }
      *(float4*)&cst[cix] = make_float4(cn[0], cn[1], cn[2], cn[3]);
      int kk = base31 + cc0;
      int kg = kk >> 3, i0 = kk & 7;
      int mf = r >> 4;
      int lane2 = kg * 16 + (r & 15);
      us* bb = hw + (size_t)(m * 16 + (j0 >> 5)) * 4096;
      U8 hh, hl;
      #pragma unroll
      for (int q = 0; q < 4; ++q) {
        us h2 = f2bf(hv[q]);
        hh.v4[q] = (short)h2;
        hl.v4[q] = (short)f2bf(hv[q] - bf2f(h2));
      }
      ast8(bb + (size_t)(mf * 2 + 0) * 512 + lane2 * 8 + i0, hh.u);
      ast8(bb + (size_t)(mf * 2 + 1) * 512 + lane2 * 8 + i0, hl.u);
      __syncthreads();
    };
    if (DO1) epi(acc1, bs1, c1, h1w);
    if (DO0) epi(acc0, bs0, c0, h0w);
  };

  // ---------- head GEMM: group-local, 16 of 32 WGs, 32 rows x 64 cols ----------
  struct HSet { ull a0, a1; s16x8 b0, b1; };
  auto headg = [&](const us* apack, const us* Wp, const float* bias,
                   float* yf, us* yp) {
    if (lb < 16) {
      const int mhl = lb >> 3, cb = lb & 7;
      const int hrow0 = row0 + mhl * 32, hj0 = cb * 64;
      f32x4 hacc[2];
      hacc[0] = {0.f, 0.f, 0.f, 0.f};
      hacc[1] = {0.f, 0.f, 0.f, 0.f};
      HSet H0, H1, H2, H3;
      auto hiss = [&](int c, HSet& R) {
        if (c >= 16) return;
        const us* a = apack + (size_t)(m * 16 + c) * 4096 + mhl * 2048;
        R.a0 = ald8(a + tid * 8);
        R.a1 = ald8(a + tid * 8 + 4);
        const us* b = Wp + (size_t)(cb * 16 + c) * 4096;
        R.b0 = *(const s16x8*)(b + tid * 8);
        R.b1 = *(const s16x8*)(b + 2048 + tid * 8);
      };
      auto hwrt = [&](int c, HSet& R) {
        if (c >= 16) return;
        int sl = c % 3;
        *(ull*)&Ash[sl][tid * 8] = R.a0;
        *(ull*)&Ash[sl][tid * 8 + 4] = R.a1;
        *(s16x8*)&Bsh[sl][0][tid * 8] = R.b0;
        *(s16x8*)&Bsh[sl][0][2048 + tid * 8] = R.b1;
      };
      auto hcmp = [&](int sl) {
        int wm = w >> 1, wn = w & 1;
        s16x8 Ah = *(const s16x8*)&Ash[sl][(wm * 2 + 0) * 512 + l * 8];
        s16x8 Al = *(const s16x8*)&Ash[sl][(wm * 2 + 1) * 512 + l * 8];
        #pragma unroll
        for (int nf = 0; nf < 2; ++nf) {
          s16x8 Bh = *(const s16x8*)&Bsh[sl][0][((wn * 2 + nf) * 2 + 0) * 512 + l * 8];
          s16x8 Bl = *(const s16x8*)&Bsh[sl][0][((wn * 2 + nf) * 2 + 1) * 512 + l * 8];
          hacc[nf] = __builtin_amdgcn_mfma_f32_16x16x32_bf16(Ah, Bh, hacc[nf], 0, 0, 0);
          hacc[nf] = __builtin_amdgcn_mfma_f32_16x16x32_bf16(Ah, Bl, hacc[nf], 0, 0, 0);
          hacc[nf] = __builtin_amdgcn_mfma_f32_16x16x32_bf16(Al, Bh, hacc[nf], 0, 0, 0);
        }
      };
      hiss(0, H0); hiss(1, H1); hiss(2, H2); hiss(3, H3);
      hwrt(0, H0); hiss(4, H0);
      hwrt(1, H1); hiss(5, H1);
      __syncthreads();
      for (int base = 0; base < 16; base += 4) {
        { int kc = base + 0; hcmp(kc % 3); hwrt(kc + 2, H2); hiss(kc + 6, H2); __syncthreads(); }
        { int kc = base + 1; hcmp(kc % 3); hwrt(kc + 2, H3); hiss(kc + 6, H3); __syncthreads(); }
        { int kc = base + 2; hcmp(kc % 3); hwrt(kc + 2, H0); hiss(kc + 6, H0); __syncthreads(); }
        { int kc = base + 3; hcmp(kc % 3); hwrt(kc + 2, H1); hiss(kc + 6, H1); __syncthreads(); }
      }
      __syncthreads();
      float* GsF = (float*)Gs;
      int wm = w >> 1, wn = w & 1;
      #pragma unroll
      for (int nf = 0; nf < 2; ++nf)
        #pragma unroll
        for (int rq = 0; rq < 4; ++rq) {
          int rr = wm * 16 + (l >> 4) * 4 + rq;
          int ccl = wn * 32 + nf * 16 + (l & 15);
          GsF[rr * 64 + ccl] = geluf(hacc[nf][rq] + bias[hj0 + ccl]);
        }
      __syncthreads();
      if (yp) {
        // packed bf16 hi/lo fragment layout (consumable as next A)
        int chunk = tid >> 7, tt = tid & 127;
        int mf_loc = tt >> 6, lane = tt & 63;
        int row = mf_loc * 16 + (lane & 15);
        int kg = lane >> 4;
        S8 hi, lo;
        #pragma unroll
        for (int i = 0; i < 8; ++i) {
          float v = GsF[row * 64 + chunk * 32 + kg * 8 + i];
          us hh = f2bf(v);
          hi.v[i] = (short)hh;
          lo.v[i] = (short)f2bf(v - bf2f(hh));
        }
        us* dst = yp + ((size_t)m * 16 + (cb * 2 + chunk)) * 4096 + mhl * 2048;
        ast8(dst + (size_t)(mf_loc * 2 + 0) * 512 + lane * 8, hi.u[0]);
        ast8(dst + (size_t)(mf_loc * 2 + 0) * 512 + lane * 8 + 4, hi.u[1]);
        ast8(dst + (size_t)(mf_loc * 2 + 1) * 512 + lane * 8, lo.u[0]);
        ast8(dst + (size_t)(mf_loc * 2 + 1) * 512 + lane * 8 + 4, lo.u[1]);
      } else {
        int rr = tid >> 3, cc0 = (tid & 7) * 8;
        float* dst = yf + (size_t)(hrow0 + rr) * 512 + hj0 + cc0;
        #pragma unroll
        for (int i = 0; i < 4; ++i) {
          U8 p;
          p.f[0] = GsF[rr * 64 + cc0 + i * 2];
          p.f[1] = GsF[rr * 64 + cc0 + i * 2 + 1];
          ast8(dst + i * 2, p.u);
        }
      }
      __syncthreads();
    }
  };

  // ---------- fc3: group-local, 2 rows per WG ----------
  auto fc3p = [&](int kidx) {
    float* GsF = (float*)Gs;
    const float* src = y2 + (size_t)(row0 + lb * 2) * 512;
    U8 v0, v1;
    v0.u = ald8(src + tid * 4);
    v1.u = ald8(src + tid * 4 + 2);
    *(ull*)&GsF[tid * 4] = v0.u;
    *(ull*)&GsF[tid * 4 + 2] = v1.u;
    __syncthreads();
    int rloc = w >> 1, o = w & 1;
    float s = 0.f;
    #pragma unroll
    for (int i = 0; i < 8; ++i) {
      int idx = l + i * 64;
      s += GsF[rloc * 512 + idx] * fc3_w[o * 512 + idx];
    }
    #pragma unroll
    for (int d = 32; d > 0; d >>= 1) s += __shfl_down(s, d, 64);
    if (l == 0)
      __hip_atomic_store(out + (size_t)(row0 + lb * 2 + rloc) * OSTR + kidx * 2 + o,
                         s + fc3_b[o], __ATOMIC_RELAXED, __HIP_MEMORY_SCOPE_AGENT);
    __syncthreads();
  };

  // ================= schedule (8 independent groups) =================
  for (int t = 0; t < 64; ++t) { fused(t > 0, true, t, false, 0); gbar(); }
  fused(true, false, 64, false, 0); gbar();   // L1(63)

  for (int kidx = 0; kidx < 17; ++kidx) {
    const us* h1cur = ((63 + kidx) & 1) ? hp1_1 : hp1_0;
    headg(h1cur, Wpf1, fc1_b, nullptr, y1p); gbar();
    headg(y1p, Wpf2, fc2_b, y2, nullptr); gbar();
    fc3p(kidx);
    if (kidx < 16) {
      gbar();
      fused(false, true, 64 + kidx, true, kidx); gbar();
      fused(true, false, 65 + kidx, false, 0); gbar();
    }
  }
}

} // namespace

extern "C" void kernel_launch(void* const* d_in, const int* in_sizes, int n_in,
                              void* d_out, int out_size, void* d_ws, size_t ws_size,
                              hipStream_t stream) {
  const float* x     = (const float*)d_in[0];
  const float* w_ih0 = (const float*)d_in[1];
  const float* w_hh0 = (const float*)d_in[2];
  const float* b_ih0 = (const float*)d_in[3];
  const float* b_hh0 = (const float*)d_in[4];
  const float* w_ih1 = (const float*)d_in[5];
  const float* w_hh1 = (const float*)d_in[6];
  const float* b_ih1 = (const float*)d_in[7];
  const float* b_hh1 = (const float*)d_in[8];
  const float* fc1_w = (const float*)d_in[9];
  const float* fc1_b = (const float*)d_in[10];
  const float* fc2_w = (const float*)d_in[11];
  const float* fc2_b = (const float*)d_in[12];
  const float* fc3_w = (const float*)d_in[13];
  const float* fc3_b = (const float*)d_in[14];
  float* out = (float*)d_out;
  char* wsb = (char*)d_ws;

  constexpr size_t MB = 1048576;
  constexpr size_t O_WP0  = 0;
  constexpr size_t O_WP1  = 4456448;
  constexpr size_t O_WPF1 = O_WP1 + 8388608;
  constexpr size_t O_WPF2 = O_WPF1 + MB;
  constexpr size_t O_BS0  = O_WPF2 + MB;
  constexpr size_t O_BS1  = O_BS0 + 8192;
  constexpr size_t O_CNT  = O_BS1 + 8192;
  constexpr size_t O_HP0B = O_CNT + 4096;           // hp0_1 (zeroed)
  constexpr size_t O_HP1B = O_HP0B + MB;            // hp1_1 (zeroed)
  constexpr size_t O_C0   = O_HP1B + MB;            // c0 (zeroed)
  constexpr size_t O_C1   = O_C0 + MB;              // c1 (zeroed)
  constexpr size_t O_HP0A = O_C1 + MB;
  constexpr size_t O_HP1A = O_HP0A + MB;
  constexpr size_t O_Y1P  = O_HP1A + MB;
  constexpr size_t O_Y2   = O_Y1P + MB;

  us* Wp0  = (us*)(wsb + O_WP0);
  us* Wp1  = (us*)(wsb + O_WP1);
  us* Wpf1 = (us*)(wsb + O_WPF1);
  us* Wpf2 = (us*)(wsb + O_WPF2);
  float* bs0 = (float*)(wsb + O_BS0);
  float* bs1 = (float*)(wsb + O_BS1);
  int* cnt   = (int*)(wsb + O_CNT);
  us* hp0_1 = (us*)(wsb + O_HP0B);
  us* hp1_1 = (us*)(wsb + O_HP1B);
  float* c0 = (float*)(wsb + O_C0);
  float* c1 = (float*)(wsb + O_C1);
  us* hp0_0 = (us*)(wsb + O_HP0A);
  us* hp1_0 = (us*)(wsb + O_HP1A);
  us* y1p   = (us*)(wsb + O_Y1P);
  float* y2 = (float*)(wsb + O_Y2);

  pack_w_kernel<<<dim3(32 * 17), 256, 0, stream>>>(w_ih0, w_hh0, 32, 512, 17, 0, Wp0);
  pack_w_kernel<<<dim3(32 * 32), 256, 0, stream>>>(w_ih1, w_hh1, 512, 512, 32, 0, Wp1);
  pack_w_kernel<<<dim3(8 * 16), 256, 0, stream>>>(fc1_w, fc1_w, 512, 512, 16, 1, Wpf1);
  pack_w_kernel<<<dim3(8 * 16), 256, 0, stream>>>(fc2_w, fc2_w, 512, 512, 16, 1, Wpf2);
  bsum_kernel<<<dim3(16), 256, 0, stream>>>(b_ih0, b_hh0, b_ih1, b_hh1, bs0, bs1);
  hipMemsetAsync(wsb + O_CNT, 0, 4096 + 4 * MB, stream);

  persist_kernel<<<dim3(256), dim3(256), 0, stream>>>(
      x, Wp0, Wp1, Wpf1, Wpf2, bs0, bs1, fc1_b, fc2_b, fc3_w, fc3_b,
      hp0_0, hp0_1, hp1_0, hp1_1, c0, c1, y1p, y2, out, cnt);
}

// Round 12
// 2520.303 us; speedup vs baseline: 2.8833x; 1.0321x over previous
//
#include <hip/hip_runtime.h>
#include <math.h>

typedef short s16x4 __attribute__((ext_vector_type(4)));
typedef short s16x8 __attribute__((ext_vector_type(8)));
typedef float f32x4 __attribute__((ext_vector_type(4)));
typedef unsigned short us;
typedef unsigned long long ull;

#define WAITVM(N) do { asm volatile("s_waitcnt vmcnt(" #N ")" ::: "memory"); __builtin_amdgcn_sched_barrier(0); } while (0)

namespace {
constexpr int T = 80, Fdim = 32, H = 512, OSTR = 34;

__device__ __forceinline__ us f2bf(float f) {
  union { float f; unsigned u; } x; x.f = f;
  unsigned u = x.u; u += 0x7fffu + ((u >> 16) & 1u);
  return (us)(u >> 16);
}
__device__ __forceinline__ float bf2f(us s) {
  union { unsigned u; float f; } x; x.u = ((unsigned)s) << 16; return x.f;
}
__device__ __forceinline__ float sigf(float v) { return 1.f / (1.f + expf(-v)); }
__device__ __forceinline__ float geluf(float v) {
  return 0.5f * v * (1.f + erff(v * 0.70710678118654752f));
}

// device-coherent 8B data movement, compiler-managed (proven green r7/r8/r11)
__device__ __forceinline__ ull ald8(const void* p) {
  return __hip_atomic_load((const ull*)p, __ATOMIC_RELAXED, __HIP_MEMORY_SCOPE_AGENT);
}
__device__ __forceinline__ void ast8(void* p, ull v) {
  __hip_atomic_store((ull*)p, v, __ATOMIC_RELAXED, __HIP_MEMORY_SCOPE_AGENT);
}

union U8 { ull u; s16x4 v4; float f[2]; };
union S8 { s16x8 v; ull u[2]; };

struct SetA { ull a0, a1, a2, a3; };
struct SetB { s16x8 b10, b11, b00, b01; };
struct HSetA { ull a0, a1; };
struct HSetB { s16x8 b0h, b0l, b1h, b1l; };

// ---------------- weight pre-pack (unchanged) ----------------
__global__ __launch_bounds__(256)
void pack_w_kernel(const float* __restrict__ w1, const float* __restrict__ w2,
                   int K1, int K2, int NKC, int head, us* __restrict__ dst) {
  int bid = blockIdx.x;
  int jb = bid / NKC, kc = bid % NKC;
  int tid = threadIdx.x;
  int strip = tid >> 6, l = tid & 63;
  int nl = l & 15, kg = l >> 4;
  int n = head ? (jb * 64 + strip * 16 + nl) : (strip * 512 + jb * 16 + nl);
  s16x8 h8, l8;
  #pragma unroll
  for (int i = 0; i < 8; ++i) {
    int k = kc * 32 + kg * 8 + i;
    float v = (k < K1) ? w1[(size_t)n * K1 + k] : w2[(size_t)n * K2 + (k - K1)];
    us h = f2bf(v);
    h8[i] = (short)h;
    l8[i] = (short)f2bf(v - bf2f(h));
  }
  size_t base = (size_t)bid * 4096;
  *(s16x8*)&dst[base + (size_t)(strip * 2 + 0) * 512 + l * 8] = h8;
  *(s16x8*)&dst[base + (size_t)(strip * 2 + 1) * 512 + l * 8] = l8;
}

__global__ __launch_bounds__(256)
void bsum_kernel(const float* bi0, const float* bh0, const float* bi1, const float* bh1,
                 float* bs0, float* bs1) {
  int i = blockIdx.x * 256 + threadIdx.x;
  if (i < 2048) bs0[i] = bi0[i] + bh0[i];
  else { int j = i - 2048; bs1[j] = bi1[j] + bh1[j]; }
}

// ---------------- persistent whole-model kernel ----------------
// 256 WGs = 8 independent groups (64 batch rows each) x 32 WGs (16 h-cols each).
// B (weights) fed per-wave directly from L2 into MFMA source registers;
// only A (shared across waves) staged through LDS.
__global__ __launch_bounds__(256, 1)
void persist_kernel(const float* __restrict__ x,
                    const us* __restrict__ Wp0, const us* __restrict__ Wp1,
                    const us* __restrict__ Wpf1, const us* __restrict__ Wpf2,
                    const float* __restrict__ bs0, const float* __restrict__ bs1,
                    const float* __restrict__ fc1_b, const float* __restrict__ fc2_b,
                    const float* __restrict__ fc3_w, const float* __restrict__ fc3_b,
                    us* hp0_0, us* hp0_1, us* hp1_0, us* hp1_1,
                    float* c0, float* c1, us* y1p, float* y2,
                    float* out, int* cnt)
{
  __shared__ __align__(16) us Ash[3][4096];
  __shared__ __align__(16) float Gs[4][64][16];

  const int tid = threadIdx.x;
  const int bid = blockIdx.x;
  const int w = tid >> 6, l = tid & 63;
  const int m = bid >> 5;                      // group 0..7 (64 rows)
  const int lb = bid & 31;                     // group-local WG id
  const int jb = (lb & 7) * 4 + (lb >> 3);     // h-col slice 0..31
  const int row0 = m * 64;
  const int j0 = jb * 16;
  const int base31 = j0 & 31;

  const us* WpJ0 = Wp0 + (size_t)jb * 17 * 4096;
  const us* WpJ1 = Wp1 + (size_t)jb * 32 * 4096;

  int ph = 0;
  auto gbar = [&]() {
    ++ph;
    WAITVM(0);
    __syncthreads();
    if (tid == 0) {
      __hip_atomic_fetch_add(&cnt[m * 64], 1, __ATOMIC_RELEASE,
                             __HIP_MEMORY_SCOPE_AGENT);
      while (__hip_atomic_load(&cnt[m * 64], __ATOMIC_RELAXED,
                               __HIP_MEMORY_SCOPE_AGENT) < 32 * ph)
        __builtin_amdgcn_s_sleep(1);
      __builtin_amdgcn_fence(__ATOMIC_ACQUIRE, "workgroup");
    }
    __syncthreads();
  };

  // ---------- fused LSTM phase: {L1(t-1) if DO1} + {L0(t) if DO0} ----------
  auto fused = [&](bool DO1, bool DO0, int t, bool use_fb, int kidx) {
    const us* h0prev = ((t + 1) & 1) ? hp0_1 : hp0_0;
    const us* h1prev = (t & 1) ? hp1_1 : hp1_0;
    us* h1w = ((t + 1) & 1) ? hp1_1 : hp1_0;
    us* h0w = (t & 1) ? hp0_1 : hp0_0;

    f32x4 acc0[4], acc1[4];
    #pragma unroll
    for (int mf = 0; mf < 4; ++mf) {
      acc0[mf] = {0.f, 0.f, 0.f, 0.f};
      acc1[mf] = {0.f, 0.f, 0.f, 0.f};
    }
    const int NP = DO1 ? 32 : 16;
    SetA A0s, A1s, A2s, A3s;
    SetB B0s, B1s;

    auto issA = [&](int c, SetA& R) {
      if (c >= NP) return;
      const us* a = ((c < 16) ? h0prev : h1prev) + (size_t)(m * 16 + (c & 15)) * 4096;
      R.a0 = ald8(a + tid * 8);
      R.a1 = ald8(a + tid * 8 + 4);
      R.a2 = ald8(a + 2048 + tid * 8);
      R.a3 = ald8(a + 2048 + tid * 8 + 4);
    };
    auto issB = [&](int c, SetB& R) {
      if (c >= NP) return;
      if (DO1) { const us* b = WpJ1 + (size_t)c * 4096 + w * 1024 + l * 8;
                 R.b10 = *(const s16x8*)(b);
                 R.b11 = *(const s16x8*)(b + 512); }
      if (DO0 && c < 16) { const us* b = WpJ0 + (size_t)(c + 1) * 4096 + w * 1024 + l * 8;
                 R.b00 = *(const s16x8*)(b);
                 R.b01 = *(const s16x8*)(b + 512); }
    };
    auto wrtA = [&](int c, SetA& R) {
      if (c >= NP) return;
      int sl = c % 3;
      *(ull*)&Ash[sl][tid * 8] = R.a0;
      *(ull*)&Ash[sl][tid * 8 + 4] = R.a1;
      *(ull*)&Ash[sl][2048 + tid * 8] = R.a2;
      *(ull*)&Ash[sl][2048 + tid * 8 + 4] = R.a3;
    };
    auto lcomp = [&](int sl, SetB& B, bool c1on, bool c0on) {
      #pragma unroll
      for (int mf = 0; mf < 4; ++mf) {
        s16x8 Ah = *(const s16x8*)&Ash[sl][(mf * 2 + 0) * 512 + l * 8];
        s16x8 Al = *(const s16x8*)&Ash[sl][(mf * 2 + 1) * 512 + l * 8];
        if (c1on) {
          acc1[mf] = __builtin_amdgcn_mfma_f32_16x16x32_bf16(Ah, B.b10, acc1[mf], 0, 0, 0);
          acc1[mf] = __builtin_amdgcn_mfma_f32_16x16x32_bf16(Ah, B.b11, acc1[mf], 0, 0, 0);
          acc1[mf] = __builtin_amdgcn_mfma_f32_16x16x32_bf16(Al, B.b10, acc1[mf], 0, 0, 0);
        }
        if (c0on) {
          acc0[mf] = __builtin_amdgcn_mfma_f32_16x16x32_bf16(Ah, B.b00, acc0[mf], 0, 0, 0);
          acc0[mf] = __builtin_amdgcn_mfma_f32_16x16x32_bf16(Ah, B.b01, acc0[mf], 0, 0, 0);
          acc0[mf] = __builtin_amdgcn_mfma_f32_16x16x32_bf16(Al, B.b00, acc0[mf], 0, 0, 0);
        }
      }
    };

    // prologue: A depth-4 (chunks 0..5 in flight), B depth-2
    issA(0, A0s); issA(1, A1s); issA(2, A2s); issA(3, A3s);
    wrtA(0, A0s); issA(4, A0s);
    wrtA(1, A1s); issA(5, A1s);
    issB(0, B0s); issB(1, B1s);
    __syncthreads();
    for (int base = 0; base < NP; base += 4) {
      { int kc = base + 0; lcomp(kc % 3, B0s, DO1, DO0 && kc < 16);
        issB(kc + 2, B0s);
        wrtA(kc + 2, A2s); issA(kc + 6, A2s); __syncthreads(); }
      { int kc = base + 1; lcomp(kc % 3, B1s, DO1, DO0 && kc < 16);
        issB(kc + 2, B1s);
        wrtA(kc + 2, A3s); issA(kc + 6, A3s); __syncthreads(); }
      { int kc = base + 2; lcomp(kc % 3, B0s, DO1, DO0 && kc < 16);
        issB(kc + 2, B0s);
        wrtA(kc + 2, A0s); issA(kc + 6, A0s); __syncthreads(); }
      { int kc = base + 3; lcomp(kc % 3, B1s, DO1, DO0 && kc < 16);
        issB(kc + 2, B1s);
        wrtA(kc + 2, A1s); issA(kc + 6, A1s); __syncthreads(); }
    }

    if (DO0) {  // x chunk (L0 weight chunk 0), B direct from L2
      SetB Bx;
      { const us* b = WpJ0 + w * 1024 + l * 8;
        Bx.b00 = *(const s16x8*)(b);
        Bx.b01 = *(const s16x8*)(b + 512); }
      int srow = tid >> 2, skg = tid & 3;
      const float* xp = x + (size_t)(row0 + srow) * (T * Fdim) + (size_t)t * Fdim + skg * 8;
      float v[8];
      #pragma unroll
      for (int i = 0; i < 8; ++i) v[i] = xp[i];
      if (use_fb && skg == 0) {
        const float* op = out + (size_t)(row0 + srow) * OSTR + kidx * 2;
        v[4] = __hip_atomic_load(op, __ATOMIC_RELAXED, __HIP_MEMORY_SCOPE_AGENT);
        v[5] = __hip_atomic_load(op + 1, __ATOMIC_RELAXED, __HIP_MEMORY_SCOPE_AGENT);
      }
      s16x8 h8, l8;
      #pragma unroll
      for (int i = 0; i < 8; ++i) {
        us hh = f2bf(v[i]);
        h8[i] = (short)hh;
        l8[i] = (short)f2bf(v[i] - bf2f(hh));
      }
      int slane = skg * 16 + (srow & 15), smf = srow >> 4;
      *(s16x8*)&Ash[0][(smf * 2 + 0) * 512 + slane * 8] = h8;
      *(s16x8*)&Ash[0][(smf * 2 + 1) * 512 + slane * 8] = l8;
      __syncthreads();
      lcomp(0, Bx, false, true);
    }

    // epilogue: stash gates -> cell -> packed coherent h write
    auto epi = [&](f32x4* acc, const float* bsum, float* cst, us* hw) {
      __syncthreads();
      float bsv = bsum[w * 512 + j0 + (l & 15)];
      #pragma unroll
      for (int mf = 0; mf < 4; ++mf)
        #pragma unroll
        for (int r = 0; r < 4; ++r)
          Gs[w][mf * 16 + (l >> 4) * 4 + r][l & 15] = acc[mf][r] + bsv;
      __syncthreads();
      int r = tid >> 2, sub = tid & 3, cc0 = sub * 4;
      float gvi[4], gvf[4], gvg[4], gvo[4], cv[4], cn[4], hv[4];
      #pragma unroll
      for (int q = 0; q < 4; ++q) {
        gvi[q] = Gs[0][r][cc0 + q]; gvf[q] = Gs[1][r][cc0 + q];
        gvg[q] = Gs[2][r][cc0 + q]; gvo[q] = Gs[3][r][cc0 + q];
      }
      size_t cix = (size_t)(row0 + r) * H + j0 + cc0;
      float4 cold = *(const float4*)&cst[cix];
      cv[0] = cold.x; cv[1] = cold.y; cv[2] = cold.z; cv[3] = cold.w;
      #pragma unroll
      for (int q = 0; q < 4; ++q) {
        float c2 = sigf(gvf[q]) * cv[q] + sigf(gvi[q]) * tanhf(gvg[q]);
        cn[q] = c2;
        hv[q] = sigf(gvo[q]) * tanhf(c2);
      }
      *(float4*)&cst[cix] = make_float4(cn[0], cn[1], cn[2], cn[3]);
      int kk = base31 + cc0;
      int kg = kk >> 3, i0 = kk & 7;
      int mf = r >> 4;
      int lane2 = kg * 16 + (r & 15);
      us* bb = hw + (size_t)(m * 16 + (j0 >> 5)) * 4096;
      U8 hh, hl;
      #pragma unroll
      for (int q = 0; q < 4; ++q) {
        us h2 = f2bf(hv[q]);
        hh.v4[q] = (short)h2;
        hl.v4[q] = (short)f2bf(hv[q] - bf2f(h2));
      }
      ast8(bb + (size_t)(mf * 2 + 0) * 512 + lane2 * 8 + i0, hh.u);
      ast8(bb + (size_t)(mf * 2 + 1) * 512 + lane2 * 8 + i0, hl.u);
      __syncthreads();
    };
    if (DO1) epi(acc1, bs1, c1, h1w);
    if (DO0) epi(acc0, bs0, c0, h0w);
  };

  // ---------- head GEMM: group-local, 16 of 32 WGs, 32 rows x 64 cols ----------
  auto headg = [&](const us* apack, const us* Wp, const float* bias,
                   float* yf, us* yp) {
    if (lb < 16) {
      const int mhl = lb >> 3, cb = lb & 7;
      const int hrow0 = row0 + mhl * 32, hj0 = cb * 64;
      const int wm = w >> 1, wn = w & 1;
      f32x4 hacc[2];
      hacc[0] = {0.f, 0.f, 0.f, 0.f};
      hacc[1] = {0.f, 0.f, 0.f, 0.f};
      HSetA HA0, HA1, HA2, HA3;
      HSetB HB0, HB1;
      auto hissA = [&](int c, HSetA& R) {
        if (c >= 16) return;
        const us* a = apack + (size_t)(m * 16 + c) * 4096 + mhl * 2048;
        R.a0 = ald8(a + tid * 8);
        R.a1 = ald8(a + tid * 8 + 4);
      };
      auto hissB = [&](int c, HSetB& R) {
        if (c >= 16) return;
        const us* b = Wp + (size_t)(cb * 16 + c) * 4096 + (size_t)(wn * 2) * 1024 + l * 8;
        R.b0h = *(const s16x8*)(b);
        R.b0l = *(const s16x8*)(b + 512);
        R.b1h = *(const s16x8*)(b + 1024);
        R.b1l = *(const s16x8*)(b + 1536);
      };
      auto hwrtA = [&](int c, HSetA& R) {
        if (c >= 16) return;
        int sl = c % 3;
        *(ull*)&Ash[sl][tid * 8] = R.a0;
        *(ull*)&Ash[sl][tid * 8 + 4] = R.a1;
      };
      auto hcmp = [&](int sl, HSetB& B) {
        s16x8 Ah = *(const s16x8*)&Ash[sl][(wm * 2 + 0) * 512 + l * 8];
        s16x8 Al = *(const s16x8*)&Ash[sl][(wm * 2 + 1) * 512 + l * 8];
        hacc[0] = __builtin_amdgcn_mfma_f32_16x16x32_bf16(Ah, B.b0h, hacc[0], 0, 0, 0);
        hacc[0] = __builtin_amdgcn_mfma_f32_16x16x32_bf16(Ah, B.b0l, hacc[0], 0, 0, 0);
        hacc[0] = __builtin_amdgcn_mfma_f32_16x16x32_bf16(Al, B.b0h, hacc[0], 0, 0, 0);
        hacc[1] = __builtin_amdgcn_mfma_f32_16x16x32_bf16(Ah, B.b1h, hacc[1], 0, 0, 0);
        hacc[1] = __builtin_amdgcn_mfma_f32_16x16x32_bf16(Ah, B.b1l, hacc[1], 0, 0, 0);
        hacc[1] = __builtin_amdgcn_mfma_f32_16x16x32_bf16(Al, B.b1h, hacc[1], 0, 0, 0);
      };
      hissA(0, HA0); hissA(1, HA1); hissA(2, HA2); hissA(3, HA3);
      hwrtA(0, HA0); hissA(4, HA0);
      hwrtA(1, HA1); hissA(5, HA1);
      hissB(0, HB0); hissB(1, HB1);
      __syncthreads();
      for (int base = 0; base < 16; base += 4) {
        { int kc = base + 0; hcmp(kc % 3, HB0); hissB(kc + 2, HB0);
          hwrtA(kc + 2, HA2); hissA(kc + 6, HA2); __syncthreads(); }
        { int kc = base + 1; hcmp(kc % 3, HB1); hissB(kc + 2, HB1);
          hwrtA(kc + 2, HA3); hissA(kc + 6, HA3); __syncthreads(); }
        { int kc = base + 2; hcmp(kc % 3, HB0); hissB(kc + 2, HB0);
          hwrtA(kc + 2, HA0); hissA(kc + 6, HA0); __syncthreads(); }
        { int kc = base + 3; hcmp(kc % 3, HB1); hissB(kc + 2, HB1);
          hwrtA(kc + 2, HA1); hissA(kc + 6, HA1); __syncthreads(); }
      }
      __syncthreads();
      float* GsF = (float*)Gs;
      #pragma unroll
      for (int nf = 0; nf < 2; ++nf)
        #pragma unroll
        for (int rq = 0; rq < 4; ++rq) {
          int rr = wm * 16 + (l >> 4) * 4 + rq;
          int ccl = wn * 32 + nf * 16 + (l & 15);
          GsF[rr * 64 + ccl] = geluf(hacc[nf][rq] + bias[hj0 + ccl]);
        }
      __syncthreads();
      if (yp) {
        // packed bf16 hi/lo fragment layout (consumable as next A)
        int chunk = tid >> 7, tt = tid & 127;
        int mf_loc = tt >> 6, lane = tt & 63;
        int row = mf_loc * 16 + (lane & 15);
        int kg = lane >> 4;
        S8 hi, lo;
        #pragma unroll
        for (int i = 0; i < 8; ++i) {
          float v = GsF[row * 64 + chunk * 32 + kg * 8 + i];
          us hh = f2bf(v);
          hi.v[i] = (short)hh;
          lo.v[i] = (short)f2bf(v - bf2f(hh));
        }
        us* dst = yp + ((size_t)m * 16 + (cb * 2 + chunk)) * 4096 + mhl * 2048;
        ast8(dst + (size_t)(mf_loc * 2 + 0) * 512 + lane * 8, hi.u[0]);
        ast8(dst + (size_t)(mf_loc * 2 + 0) * 512 + lane * 8 + 4, hi.u[1]);
        ast8(dst + (size_t)(mf_loc * 2 + 1) * 512 + lane * 8, lo.u[0]);
        ast8(dst + (size_t)(mf_loc * 2 + 1) * 512 + lane * 8 + 4, lo.u[1]);
      } else {
        int rr = tid >> 3, cc0 = (tid & 7) * 8;
        float* dst = yf + (size_t)(hrow0 + rr) * 512 + hj0 + cc0;
        #pragma unroll
        for (int i = 0; i < 4; ++i) {
          U8 p;
          p.f[0] = GsF[rr * 64 + cc0 + i * 2];
          p.f[1] = GsF[rr * 64 + cc0 + i * 2 + 1];
          ast8(dst + i * 2, p.u);
        }
      }
      __syncthreads();
    }
  };

  // ---------- fc3: group-local, 2 rows per WG ----------
  auto fc3p = [&](int kidx) {
    float* GsF = (float*)Gs;
    const float* src = y2 + (size_t)(row0 + lb * 2) * 512;
    U8 v0, v1;
    v0.u = ald8(src + tid * 4);
    v1.u = ald8(src + tid * 4 + 2);
    *(ull*)&GsF[tid * 4] = v0.u;
    *(ull*)&GsF[tid * 4 + 2] = v1.u;
    __syncthreads();
    int rloc = w >> 1, o = w & 1;
    float s = 0.f;
    #pragma unroll
    for (int i = 0; i < 8; ++i) {
      int idx = l + i * 64;
      s += GsF[rloc * 512 + idx] * fc3_w[o * 512 + idx];
    }
    #pragma unroll
    for (int d = 32; d > 0; d >>= 1) s += __shfl_down(s, d, 64);
    if (l == 0)
      __hip_atomic_store(out + (size_t)(row0 + lb * 2 + rloc) * OSTR + kidx * 2 + o,
                         s + fc3_b[o], __ATOMIC_RELAXED, __HIP_MEMORY_SCOPE_AGENT);
    __syncthreads();
  };

  // ================= schedule (8 independent groups) =================
  for (int t = 0; t < 64; ++t) { fused(t > 0, true, t, false, 0); gbar(); }
  fused(true, false, 64, false, 0); gbar();   // L1(63)

  for (int kidx = 0; kidx < 17; ++kidx) {
    const us* h1cur = ((63 + kidx) & 1) ? hp1_1 : hp1_0;
    headg(h1cur, Wpf1, fc1_b, nullptr, y1p); gbar();
    headg(y1p, Wpf2, fc2_b, y2, nullptr); gbar();
    fc3p(kidx);
    if (kidx < 16) {
      gbar();
      fused(false, true, 64 + kidx, true, kidx); gbar();
      fused(true, false, 65 + kidx, false, 0); gbar();
    }
  }
}

} // namespace

extern "C" void kernel_launch(void* const* d_in, const int* in_sizes, int n_in,
                              void* d_out, int out_size, void* d_ws, size_t ws_size,
                              hipStream_t stream) {
  const float* x     = (const float*)d_in[0];
  const float* w_ih0 = (const float*)d_in[1];
  const float* w_hh0 = (const float*)d_in[2];
  const float* b_ih0 = (const float*)d_in[3];
  const float* b_hh0 = (const float*)d_in[4];
  const float* w_ih1 = (const float*)d_in[5];
  const float* w_hh1 = (const float*)d_in[6];
  const float* b_ih1 = (const float*)d_in[7];
  const float* b_hh1 = (const float*)d_in[8];
  const float* fc1_w = (const float*)d_in[9];
  const float* fc1_b = (const float*)d_in[10];
  const float* fc2_w = (const float*)d_in[11];
  const float* fc2_b = (const float*)d_in[12];
  const float* fc3_w = (const float*)d_in[13];
  const float* fc3_b = (const float*)d_in[14];
  float* out = (float*)d_out;
  char* wsb = (char*)d_ws;

  constexpr size_t MB = 1048576;
  constexpr size_t O_WP0  = 0;
  constexpr size_t O_WP1  = 4456448;
  constexpr size_t O_WPF1 = O_WP1 + 8388608;
  constexpr size_t O_WPF2 = O_WPF1 + MB;
  constexpr size_t O_BS0  = O_WPF2 + MB;
  constexpr size_t O_BS1  = O_BS0 + 8192;
  constexpr size_t O_CNT  = O_BS1 + 8192;
  constexpr size_t O_HP0B = O_CNT + 4096;           // hp0_1 (zeroed)
  constexpr size_t O_HP1B = O_HP0B + MB;            // hp1_1 (zeroed)
  constexpr size_t O_C0   = O_HP1B + MB;            // c0 (zeroed)
  constexpr size_t O_C1   = O_C0 + MB;              // c1 (zeroed)
  constexpr size_t O_HP0A = O_C1 + MB;
  constexpr size_t O_HP1A = O_HP0A + MB;
  constexpr size_t O_Y1P  = O_HP1A + MB;
  constexpr size_t O_Y2   = O_Y1P + MB;

  us* Wp0  = (us*)(wsb + O_WP0);
  us* Wp1  = (us*)(wsb + O_WP1);
  us* Wpf1 = (us*)(wsb + O_WPF1);
  us* Wpf2 = (us*)(wsb + O_WPF2);
  float* bs0 = (float*)(wsb + O_BS0);
  float* bs1 = (float*)(wsb + O_BS1);
  int* cnt   = (int*)(wsb + O_CNT);
  us* hp0_1 = (us*)(wsb + O_HP0B);
  us* hp1_1 = (us*)(wsb + O_HP1B);
  float* c0 = (float*)(wsb + O_C0);
  float* c1 = (float*)(wsb + O_C1);
  us* hp0_0 = (us*)(wsb + O_HP0A);
  us* hp1_0 = (us*)(wsb + O_HP1A);
  us* y1p   = (us*)(wsb + O_Y1P);
  float* y2 = (float*)(wsb + O_Y2);

  pack_w_kernel<<<dim3(32 * 17), 256, 0, stream>>>(w_ih0, w_hh0, 32, 512, 17, 0, Wp0);
  pack_w_kernel<<<dim3(32 * 32), 256, 0, stream>>>(w_ih1, w_hh1, 512, 512, 32, 0, Wp1);
  pack_w_kernel<<<dim3(8 * 16), 256, 0, stream>>>(fc1_w, fc1_w, 512, 512, 16, 1, Wpf1);
  pack_w_kernel<<<dim3(8 * 16), 256, 0, stream>>>(fc2_w, fc2_w, 512, 512, 16, 1, Wpf2);
  bsum_kernel<<<dim3(16), 256, 0, stream>>>(b_ih0, b_hh0, b_ih1, b_hh1, bs0, bs1);
  hipMemsetAsync(wsb + O_CNT, 0, 4096 + 4 * MB, stream);

  persist_kernel<<<dim3(256), dim3(256), 0, stream>>>(
      x, Wp0, Wp1, Wpf1, Wpf2, bs0, bs1, fc1_b, fc2_b, fc3_w, fc3_b,
      hp0_0, hp0_1, hp1_0, hp1_1, c0, c1, y1p, y2, out, cnt);
}